// Round 16
// baseline (328.123 us; speedup 1.0000x reference)
//
#include <hip/hip_runtime.h>

// HyperLSTMCell on MI355X (gfx950).  B=65536, D=128, H=256, Z=128, E=16.
// All inputs/outputs f32; internal GEMMs bf16 MFMA (16x16x32).
//
// r16 = r15 (3 waves/SIMD: dsc in LDS, (256,3), 48 KB LDS) + latency hiding:
//   - half-split B double-buffer: compute h0(B0) -> reload B0<-B(s+1).h0 ->
//     compute h1(B1) -> reload B1. Same 32 VGPR; B(s+1) gains ~half-step cover.
//   - skip redundant A-stages: steps 2,3 reuse c0/c1 tiles staged for 0,1
//     (ring-2 parity preserves them; first in-loop stage is stage(4) at s=3).
//   - epilogue c0/chat0 prefetch at top of last step (16 scalar loads ride
//     under the final sweeps).
// Barrier ledger (k2, ring-2): VM_BAR(8) at step end: in-flight =
// stageA(s+1) 2 + B(s+1) 8 -> forces the stage (cross-wave LDS visibility).
// k1 (ring-3): transitive forcing via compiler B-waits (r15-validated).
//
// d_out (f32): h1 [B,256] | c1 [B,256] | hhat1 [B,128] | chat1 [B,128]

typedef unsigned short u16;
typedef __attribute__((ext_vector_type(8))) short bf16x8;   // 8 bf16 (4 VGPRs)
typedef __attribute__((ext_vector_type(4))) float f32x4;

#define BATCH 65536

__device__ __forceinline__ u16 f2b(float f) {           // f32 -> bf16 bits, RNE
  unsigned u = __float_as_uint(f);
  u += 0x7fffu + ((u >> 16) & 1u);
  return (u16)(u >> 16);
}
__device__ __forceinline__ unsigned pk2(float a, float b) {   // 2xf32 -> packed bf16
  return (unsigned)f2b(a) | ((unsigned)f2b(b) << 16);
}
__device__ __forceinline__ float upk_lo(unsigned u) { return __uint_as_float(u << 16); }
__device__ __forceinline__ float upk_hi(unsigned u) { return __uint_as_float(u & 0xffff0000u); }
__device__ __forceinline__ float sigf(float x) { return 1.0f / (1.0f + __expf(-x)); }
__device__ __forceinline__ float tanhfast(float x) {    // clamped exp-based tanh
  float xc = fminf(fmaxf(x, -15.f), 15.f);
  float e = __expf(2.f * xc);
  return (e - 1.f) / (e + 1.f);
}
// LDS XOR swizzle for [row][64] bf16 A-tiles (G4).
__device__ __forceinline__ int swz(int r, int c) { return r * 64 + (c ^ ((r & 7) << 3)); }

// counted-vmcnt barrier (T4) + scheduler fence (rule #18)
#define VM_BAR(N) do { \
  asm volatile("s_waitcnt vmcnt(" #N ")" ::: "memory"); \
  __builtin_amdgcn_s_barrier(); \
  __builtin_amdgcn_sched_barrier(0); } while (0)

// async global->LDS, 16B per lane (m97: global_load_lds_dwordx4)
__device__ __forceinline__ void gl_lds16(const u16* g, u16* l) {
  __builtin_amdgcn_global_load_lds(
      (const __attribute__((address_space(1))) void*)g,
      (__attribute__((address_space(3))) void*)l, 16, 0, 0);
}
// stage 64x64 A-tile (8 KB) from row-major bf16 (stride ldk) into the swizzled
// LDS image: linear LDS dest + XOR-permuted GLOBAL source chunks (m173).
__device__ __forceinline__ void stageA(const u16* base, int ldk, u16* lA, int t) {
  const int r = t >> 3, q = t & 7, wid = t >> 6;
  const int qs = (q ^ (r & 7)) << 3;                 // (r+32)&7 == r&7
  gl_lds16(base + (size_t)r * ldk + qs, lA + wid * 512);
  gl_lds16(base + (size_t)(r + 32) * ldk + qs, lA + 2048 + wid * 512);
}

// ---------------------------------------------------------------------------
// pre: fused input-cast + weight prep (fragment-major B).  [r10/r15, unchanged]
// ---------------------------------------------------------------------------
__global__ __launch_bounds__(256) void hlstm_pre(
    const float* __restrict__ hhat0, const float* __restrict__ h0,
    const float* __restrict__ x, u16* __restrict__ abuf,
    const float* __restrict__ hweight, const float* __restrict__ hbias,
    const float* __restrict__ zw_h, const float* __restrict__ zw_x, const float* __restrict__ zw_b,
    const float* __restrict__ zb_h, const float* __restrict__ zb_x,
    const float* __restrict__ dw_h, const float* __restrict__ dw_x, const float* __restrict__ dw_b,
    const float* __restrict__ weight, const float* __restrict__ bias,
    u16* __restrict__ hw_fr, float* __restrict__ hbias_r,
    u16* __restrict__ w_fr,  float* __restrict__ bias_r,
    u16* __restrict__ whp_fr, u16* __restrict__ wxp_fr, u16* __restrict__ wbp_fr,
    float* __restrict__ bhp_r, float* __restrict__ bxp_r)
{
  if (blockIdx.x < 4096) {
    // ---- cast part: abuf[B][512] = bf16([hhat0 | h0 | x])
    const size_t stride = (size_t)4096 * 256;
    for (size_t i = (size_t)blockIdx.x * 256 + threadIdx.x;
         i < (size_t)BATCH * 64; i += stride) {
      const size_t b = i >> 6; const int c = (int)(i & 63);
      const float* src;
      if (c < 16)      src = hhat0 + b * 128 + c * 8;
      else if (c < 48) src = h0 + b * 256 + (size_t)(c - 16) * 8;
      else             src = x + b * 128 + (size_t)(c - 48) * 8;
      float4 v0 = ((const float4*)src)[0];
      float4 v1 = ((const float4*)src)[1];
      alignas(16) u16 o[8] = {f2b(v0.x), f2b(v0.y), f2b(v0.z), f2b(v0.w),
                              f2b(v1.x), f2b(v1.y), f2b(v1.z), f2b(v1.w)};
      *(uint4*)(abuf + i * 8) = *(const uint4*)o;
    }
    return;
  }
  // ---- prep part: fragment-major images.
  const int tid = (blockIdx.x - 4096) * 256 + threadIdx.x;
  const int nt  = 512 * 256;

  // hw_fr: 16 tiles (hb*8+s), phys col = g*128 + hb*64 + hh
  for (int i = tid; i < 16 * 16384; i += nt) {
    int tile = i >> 14, r = i & 16383;
    int wc = r >> 12, h = (r >> 11) & 1, g = (r >> 9) & 3;
    int lane = (r >> 3) & 63, j = r & 7;
    int hb = tile >> 3, s = tile & 7;
    int k = s * 64 + h * 32 + (lane >> 4) * 8 + j;
    int col = g * 128 + hb * 64 + wc * 16 + (lane & 15);
    hw_fr[i] = f2b(hweight[k * 512 + col]);
  }
  // w_fr: 24 tiles (hb*6+s), phys col = g*256 + hb*64 + hh
  for (int i = tid; i < 24 * 16384; i += nt) {
    int tile = i >> 14, r = i & 16383;
    int wc = r >> 12, h = (r >> 11) & 1, g = (r >> 9) & 3;
    int lane = (r >> 3) & 63, j = r & 7;
    int hb = tile / 6, s = tile % 6;
    int k = s * 64 + h * 32 + (lane >> 4) * 8 + j;
    int col = g * 256 + hb * 64 + wc * 16 + (lane & 15);
    w_fr[i] = f2b(weight[k * 1024 + col]);
  }
  // folded hyper fragments: 3 mats x 8 tiles (hb*2+s); W'[k][(g,h)] = sum_e zw*dw
  for (int i = tid; i < 3 * 8 * 16384; i += nt) {
    int mat = i / (8 * 16384), rem = i % (8 * 16384);
    int tile = rem >> 14, r = rem & 16383;
    int wc = r >> 12, h = (r >> 11) & 1, g = (r >> 9) & 3;
    int lane = (r >> 3) & 63, j = r & 7;
    int hb = tile >> 1, s = tile & 1;
    int k = s * 64 + h * 32 + (lane >> 4) * 8 + j;       // 0..127
    int colh = hb * 64 + wc * 16 + (lane & 15);
    const float* zw = (mat == 0) ? zw_h : (mat == 1) ? zw_x : zw_b;
    const float* dw = (mat == 0) ? dw_h : (mat == 1) ? dw_x : dw_b;
    float sv = 0.f;
#pragma unroll
    for (int e = 0; e < 16; ++e)
      sv += zw[k * 64 + g * 16 + e] * dw[g * 4096 + e * 256 + colh];
    u16* dst = (mat == 0) ? whp_fr : (mat == 1) ? wxp_fr : wbp_fr;
    dst[rem] = f2b(sv);
  }
  // bias folds (virtual order hb*256 + g*64 + hh)
  for (int i = tid; i < 1024; i += nt) {
    int hb = i >> 8, g = (i >> 6) & 3, hh = i & 63;
    int h = hb * 64 + hh;
    float sh = 0.f, sx = 0.f;
#pragma unroll
    for (int e = 0; e < 16; ++e) {
      sh += zb_h[g * 16 + e] * dw_h[g * 4096 + e * 256 + h];
      sx += zb_x[g * 16 + e] * dw_x[g * 4096 + e * 256 + h];
    }
    bhp_r[i] = sh; bxp_r[i] = sx;
    bias_r[i] = bias[g * 256 + h];
  }
  for (int i = tid; i < 512; i += nt) {
    int gate = (i >> 6) & 3, hb = i >> 8, hh = i & 63;
    hbias_r[i] = hbias[gate * 128 + hb * 64 + hh];
  }
}

// ---------------------------------------------------------------------------
// k1: hyper GEMM (K=512, 8 steps) + hyper LSTM. 2048 blocks x 256 threads.
// A: LDS ring-3; B: half-split double-buffered reg fragments; chat0 prefetch.
// ---------------------------------------------------------------------------
__global__ __launch_bounds__(256, 3) void hlstm_k1(
    const u16* __restrict__ abuf, const float* __restrict__ chat0,
    const u16* __restrict__ hw_fr, const float* __restrict__ hbias_r,
    float* __restrict__ d_out, u16* __restrict__ hbuf)
{
  __shared__ alignas(16) u16 lA[3][64 * 64];
  const int f = blockIdx.x;                 // 0..2047
  const int xcd = f & 7, s2 = f >> 3;
  const int rb = xcd * 128 + (s2 >> 1), hb = s2 & 1;
  const int t = threadIdx.x;
  const int lane = t & 63, wc = t >> 6;
  const int lr = lane & 15, kg = lane >> 4;

  f32x4 acc[4][4];
  const f32x4 zzero = {0.f, 0.f, 0.f, 0.f};
#pragma unroll
  for (int mf = 0; mf < 4; ++mf)
#pragma unroll
    for (int g = 0; g < 4; ++g) acc[mf][g] = zzero;

  const u16* arow = abuf + (size_t)rb * 64 * 512;

  bf16x8 B0[4], B1[4];
  f32x4 chr[4];
  auto loadBh = [&](bf16x8 (&Bh)[4], const u16* bt, int h) {
#pragma unroll
    for (int g = 0; g < 4; ++g)
      Bh[g] = *(const bf16x8*)&bt[((wc * 2 + h) * 4 + g) * 512 + lane * 8];
  };
  auto sweepH = [&](int h, const bf16x8 (&Bh)[4], const u16* cA) {
#pragma unroll
    for (int mf = 0; mf < 4; ++mf) {
      bf16x8 afr = *(const bf16x8*)&cA[swz(mf * 16 + lr, h * 32 + kg * 8)];
#pragma unroll
      for (int g = 0; g < 4; ++g)
        acc[mf][g] = __builtin_amdgcn_mfma_f32_16x16x32_bf16(afr, Bh[g], acc[mf][g], 0, 0, 0);
    }
  };

  const int zc = hb * 64 + wc * 16 + lr;

  // prologue: A(0), A(1) staged; B(0) both halves issued.
  stageA(arow + 0 * 64, 512, lA[0], t);
  stageA(arow + 1 * 64, 512, lA[1], t);
  loadBh(B0, hw_fr + (size_t)(hb * 8 + 0) * 16384, 0);
  loadBh(B1, hw_fr + (size_t)(hb * 8 + 0) * 16384, 1);
  VM_BAR(10);                               // forces stage(0); rest rides

#pragma unroll
  for (int ks = 0; ks < 8; ++ks) {
    if (ks < 6) stageA(arow + (ks + 2) * 64, 512, lA[(ks + 2) % 3], t);
    if (ks == 7) {                          // prefetch chat0 for epilogue
#pragma unroll
      for (int mf = 0; mf < 4; ++mf)
#pragma unroll
        for (int r = 0; r < 4; ++r)
          chr[mf][r] = chat0[(size_t)(rb * 64 + mf * 16 + kg * 4 + r) * 128 + zc];
    }
    __builtin_amdgcn_s_setprio(1);
    sweepH(0, B0, lA[ks % 3]);
    if (ks < 7) loadBh(B0, hw_fr + (size_t)(hb * 8 + ks + 1) * 16384, 0);
    sweepH(1, B1, lA[ks % 3]);
    if (ks < 7) loadBh(B1, hw_fr + (size_t)(hb * 8 + ks + 1) * 16384, 1);
    __builtin_amdgcn_s_setprio(0);
    if (ks < 7) VM_BAR(10);
  }

  float hb4[4];
#pragma unroll
  for (int g = 0; g < 4; ++g) hb4[g] = hbias_r[hb * 256 + g * 64 + wc * 16 + lr];
  float* out_hh = d_out + (size_t)BATCH * 512;
  float* out_ch = d_out + (size_t)BATCH * 640;
#pragma unroll
  for (int mf = 0; mf < 4; ++mf)
#pragma unroll
    for (int r = 0; r < 4; ++r) {
      const int row = rb * 64 + mf * 16 + kg * 4 + r;
      const float gi = acc[mf][0][r] + hb4[0];
      const float gg = acc[mf][1][r] + hb4[1];
      const float gf = acc[mf][2][r] + hb4[2];
      const float go = acc[mf][3][r] + hb4[3];
      const float c1v = sigf(gf) * chr[mf][r] + sigf(gi) * tanhfast(gg);
      const float h1v = sigf(go) * tanhfast(c1v);
      out_hh[(size_t)row * 128 + zc] = h1v;
      out_ch[(size_t)row * 128 + zc] = c1v;
      hbuf[(size_t)row * 128 + zc] = f2b(h1v);
    }
}

// ---------------------------------------------------------------------------
// k2: hyper-first 12 K-steps (s0-1 d_yh -> dsc ; s2-3 d_yx -> dsc ; s4-9 main
// gpre ; s9 acc*=dsc ; s10-11 d_yb MFMA C-in). 4096 blocks x 256 threads.
// A: LDS ring-2 (stage skips for content-reuse at s2,s3); B: half-split dbuf;
// dsc in per-thread LDS; c0 prefetch at s=11. LDS 48 KB -> 3 blocks/CU.
// ---------------------------------------------------------------------------
__global__ __launch_bounds__(256, 3) void hlstm_k2(
    const u16* __restrict__ abuf, const u16* __restrict__ hbuf,
    const float* __restrict__ c0,
    const u16* __restrict__ w_fr, const float* __restrict__ bias_r,
    const u16* __restrict__ whp_fr, const u16* __restrict__ wxp_fr, const u16* __restrict__ wbp_fr,
    const float* __restrict__ bhp_r, const float* __restrict__ bxp_r,
    float* __restrict__ d_out)
{
  __shared__ alignas(16) u16 lA[2][64 * 64];     // 16 KB (ring-2)
  __shared__ alignas(16) unsigned ldsc[8192];    // 32 KB packed dscale
  const int f = blockIdx.x;                 // 0..4095
  const int xcd = f & 7, s4 = f >> 3;
  const int rb = xcd * 128 + (s4 >> 2), hb = s4 & 3;
  const int t = threadIdx.x;
  const int lane = t & 63, wc = t >> 6;
  const int lr = lane & 15, kg = lane >> 4;

  const u16* amain = abuf + (size_t)rb * 64 * 512 + 128;   // [h0|x] cols, ld 512
  const u16* ahyp  = hbuf + (size_t)rb * 64 * 128;         // ld 128

  // steps: 0..3 hyper (Wh',Wx'), 4..9 main, 10..11 hyper (Wb')
  auto aptr = [&](int s) -> const u16* {
    if (s >= 4 && s < 10) return amain + (s - 4) * 64;
    return ahyp + (s & 1) * 64;
  };
  auto aldk = [&](int s) -> int { return (s >= 4 && s < 10) ? 512 : 128; };
  auto bptr = [&](int s) -> const u16* {
    if (s < 2)  return whp_fr + (size_t)(hb * 2 + s) * 16384;
    if (s < 4)  return wxp_fr + (size_t)(hb * 2 + s - 2) * 16384;
    if (s < 10) return w_fr  + (size_t)(hb * 6 + s - 4) * 16384;
    return wbp_fr + (size_t)(hb * 2 + s - 10) * 16384;
  };

  f32x4 acc[4][4];
  const f32x4 zzero = {0.f, 0.f, 0.f, 0.f};
#pragma unroll
  for (int mf = 0; mf < 4; ++mf)
#pragma unroll
    for (int g = 0; g < 4; ++g) acc[mf][g] = zzero;

  bf16x8 B0[4], B1[4];
  f32x4 c0r[4];
  auto loadBh = [&](bf16x8 (&Bh)[4], const u16* bt, int h) {
#pragma unroll
    for (int g = 0; g < 4; ++g)
      Bh[g] = *(const bf16x8*)&bt[((wc * 2 + h) * 4 + g) * 512 + lane * 8];
  };
  auto sweepH = [&](int h, const bf16x8 (&Bh)[4], const u16* cA) {
#pragma unroll
    for (int mf = 0; mf < 4; ++mf) {
      bf16x8 afr = *(const bf16x8*)&cA[swz(mf * 16 + lr, h * 32 + kg * 8)];
#pragma unroll
      for (int g = 0; g < 4; ++g)
        acc[mf][g] = __builtin_amdgcn_mfma_f32_16x16x32_bf16(afr, Bh[g], acc[mf][g], 0, 0, 0);
    }
  };

  const int hcol = hb * 64 + wc * 16 + lr;

  // prologue: A(0)->lA0, A(1)->lA1 staged; B(0) both halves issued.
  stageA(aptr(0), aldk(0), lA[0], t);
  stageA(aptr(1), aldk(1), lA[1], t);
  loadBh(B0, bptr(0), 0);
  loadBh(B1, bptr(0), 1);
  VM_BAR(10);                               // forces stage(0); rest rides

#pragma unroll
  for (int s = 0; s < 12; ++s) {
    // stage(s+1): s+1=1 pre-staged; s+1 in {2,3} content-reuse (c0/c1 intact)
    if (s >= 3 && s < 11) stageA(aptr(s + 1), aldk(s + 1), lA[(s + 1) & 1], t);
    if (s == 2 || s == 4) {                 // new phase: re-zero single acc
#pragma unroll
      for (int mf = 0; mf < 4; ++mf)
#pragma unroll
        for (int g = 0; g < 4; ++g) acc[mf][g] = zzero;
    }
    if (s == 11) {                          // prefetch c0 for epilogue
#pragma unroll
      for (int mf = 0; mf < 4; ++mf)
#pragma unroll
        for (int r = 0; r < 4; ++r)
          c0r[mf][r] = c0[(size_t)(rb * 64 + mf * 16 + kg * 4 + r) * 256 + hcol];
    }
    __builtin_amdgcn_s_setprio(1);
    sweepH(0, B0, lA[s & 1]);
    if (s < 11) loadBh(B0, bptr(s + 1), 0);
    sweepH(1, B1, lA[s & 1]);
    if (s < 11) loadBh(B1, bptr(s + 1), 1);
    __builtin_amdgcn_s_setprio(0);

    if (s == 1) {                           // ldsc = pack(d_yh + bh')
      float bh4[4];
#pragma unroll
      for (int g = 0; g < 4; ++g) bh4[g] = bhp_r[hb * 256 + g * 64 + wc * 16 + lr];
#pragma unroll
      for (int mf = 0; mf < 4; ++mf)
#pragma unroll
        for (int gp = 0; gp < 2; ++gp) {
          const int g0 = gp * 2, g1 = gp * 2 + 1;
          uint4 v;
          v.x = pk2(acc[mf][g0][0] + bh4[g0], acc[mf][g0][1] + bh4[g0]);
          v.y = pk2(acc[mf][g0][2] + bh4[g0], acc[mf][g0][3] + bh4[g0]);
          v.z = pk2(acc[mf][g1][0] + bh4[g1], acc[mf][g1][1] + bh4[g1]);
          v.w = pk2(acc[mf][g1][2] + bh4[g1], acc[mf][g1][3] + bh4[g1]);
          *(uint4*)&ldsc[(mf * 2 + gp) * 1024 + t * 4] = v;
        }
    } else if (s == 3) {                    // ldsc *= (d_yx + bx')
      float bx4[4];
#pragma unroll
      for (int g = 0; g < 4; ++g) bx4[g] = bxp_r[hb * 256 + g * 64 + wc * 16 + lr];
#pragma unroll
      for (int mf = 0; mf < 4; ++mf)
#pragma unroll
        for (int gp = 0; gp < 2; ++gp) {
          const int g0 = gp * 2, g1 = gp * 2 + 1;
          uint4 v = *(const uint4*)&ldsc[(mf * 2 + gp) * 1024 + t * 4];
          v.x = pk2(upk_lo(v.x) * (acc[mf][g0][0] + bx4[g0]),
                    upk_hi(v.x) * (acc[mf][g0][1] + bx4[g0]));
          v.y = pk2(upk_lo(v.y) * (acc[mf][g0][2] + bx4[g0]),
                    upk_hi(v.y) * (acc[mf][g0][3] + bx4[g0]));
          v.z = pk2(upk_lo(v.z) * (acc[mf][g1][0] + bx4[g1]),
                    upk_hi(v.z) * (acc[mf][g1][1] + bx4[g1]));
          v.w = pk2(upk_lo(v.w) * (acc[mf][g1][2] + bx4[g1]),
                    upk_hi(v.w) * (acc[mf][g1][3] + bx4[g1]));
          *(uint4*)&ldsc[(mf * 2 + gp) * 1024 + t * 4] = v;
        }
    } else if (s == 9) {                    // acc(gpre) *= dscale
#pragma unroll
      for (int mf = 0; mf < 4; ++mf)
#pragma unroll
        for (int gp = 0; gp < 2; ++gp) {
          const int g0 = gp * 2, g1 = gp * 2 + 1;
          uint4 v = *(const uint4*)&ldsc[(mf * 2 + gp) * 1024 + t * 4];
          acc[mf][g0][0] *= upk_lo(v.x);
          acc[mf][g0][1] *= upk_hi(v.x);
          acc[mf][g0][2] *= upk_lo(v.y);
          acc[mf][g0][3] *= upk_hi(v.y);
          acc[mf][g1][0] *= upk_lo(v.z);
          acc[mf][g1][1] *= upk_hi(v.z);
          acc[mf][g1][2] *= upk_lo(v.w);
          acc[mf][g1][3] *= upk_hi(v.w);
        }
    }
    if (s < 11) VM_BAR(8);                  // forces stageA(s+1) (when staged)
  }

  // ---- epilogue: main LSTM cell (acc = gpre*dscale + d_yb)
  float b4[4];
#pragma unroll
  for (int g = 0; g < 4; ++g) b4[g] = bias_r[hb * 256 + g * 64 + wc * 16 + lr];
  float* out_c1 = d_out + (size_t)BATCH * 256;
#pragma unroll
  for (int mf = 0; mf < 4; ++mf)
#pragma unroll
    for (int r = 0; r < 4; ++r) {
      const int row = rb * 64 + mf * 16 + kg * 4 + r;
      const float gi = acc[mf][0][r] + b4[0];
      const float gg = acc[mf][1][r] + b4[1];
      const float gf = acc[mf][2][r] + b4[2];
      const float go = acc[mf][3][r] + b4[3];
      const float c1v = sigf(gf) * c0r[mf][r] + sigf(gi) * tanhfast(gg);
      const float h1v = sigf(go) * tanhfast(c1v);
      d_out[(size_t)row * 256 + hcol]  = h1v;
      out_c1[(size_t)row * 256 + hcol] = c1v;
    }
}

// ---------------------------------------------------------------------------
extern "C" void kernel_launch(void* const* d_in, const int* in_sizes, int n_in,
                              void* d_out, int out_size, void* d_ws, size_t ws_size,
                              hipStream_t stream)
{
  (void)in_sizes; (void)n_in; (void)out_size; (void)ws_size;
  const float* x       = (const float*)d_in[0];
  const float* h0      = (const float*)d_in[1];
  const float* c0      = (const float*)d_in[2];
  const float* hhat0   = (const float*)d_in[3];
  const float* chat0   = (const float*)d_in[4];
  const float* hweight = (const float*)d_in[5];
  const float* hbias   = (const float*)d_in[6];
  const float* zw_h    = (const float*)d_in[7];
  const float* zw_x    = (const float*)d_in[8];
  const float* zw_b    = (const float*)d_in[9];
  const float* zb_h    = (const float*)d_in[10];
  const float* zb_x    = (const float*)d_in[11];
  const float* dw_h    = (const float*)d_in[12];
  const float* dw_x    = (const float*)d_in[13];
  const float* dw_b    = (const float*)d_in[14];
  const float* weight  = (const float*)d_in[15];
  const float* bias    = (const float*)d_in[16];

  // workspace layout (bytes, 16B-aligned); total ~86 MB
  char* wsb = (char*)d_ws;
  u16*   abuf    = (u16*)(wsb + 0);              // B*512*2   = 67108864
  u16*   hbuf    = (u16*)(wsb + 67108864);       // B*128*2   = 16777216
  u16*   hw_fr   = (u16*)(wsb + 83886080);       // 16*16384*2 = 524288
  u16*   w_fr    = (u16*)(wsb + 84410368);       // 24*16384*2 = 786432
  u16*   whp_fr  = (u16*)(wsb + 85196800);       // 8*16384*2  = 262144
  u16*   wxp_fr  = (u16*)(wsb + 85458944);
  u16*   wbp_fr  = (u16*)(wsb + 85721088);
  float* hbias_r = (float*)(wsb + 85983232);     // 512*4
  float* bias_r  = (float*)(wsb + 85985280);     // 1024*4
  float* bhp_r   = (float*)(wsb + 85989376);     // 1024*4
  float* bxp_r   = (float*)(wsb + 85993472);     // 1024*4

  hlstm_pre<<<dim3(4608), dim3(256), 0, stream>>>(
      hhat0, h0, x, abuf,
      hweight, hbias, zw_h, zw_x, zw_b, zb_h, zb_x, dw_h, dw_x, dw_b, weight, bias,
      hw_fr, hbias_r, w_fr, bias_r, whp_fr, wxp_fr, wbp_fr, bhp_r, bxp_r);

  hlstm_k1<<<dim3(2048), dim3(256), 0, stream>>>(
      abuf, chat0, hw_fr, hbias_r, (float*)d_out, hbuf);

  hlstm_k2<<<dim3(4096), dim3(256), 0, stream>>>(
      abuf, hbuf, c0, w_fr, bias_r, whp_fr, wxp_fr, wbp_fr, bhp_r, bxp_r, (float*)d_out);
}

// Round 17
// 264.317 us; speedup vs baseline: 1.2414x; 1.2414x over previous
//
#include <hip/hip_runtime.h>

// HyperLSTMCell on MI355X (gfx950).  B=65536, D=128, H=256, Z=128, E=16.
// All inputs/outputs f32; internal GEMMs bf16 MFMA (16x16x32).
//
// r17 = r15 (best known: 3 waves/SIMD via dsc-in-LDS + (256,3), 48 KB LDS,
// ring-2 A + single-buffered reg B, counted vmcnt) + ONE register-free tweak:
// k2 skips the redundant A-stages at steps 2,3 (content-reuse: hyper steps
// 0..3 read ahyp cols {0,64,0,64}; ring-2 parity keeps tiles 0,1 in place).
// r16's half-split B + epilogue prefetch REVERTED (caused ~150 MB scratch
// spill under the (256,3) cap: WRITE 282 MB vs 131).
//
// d_out (f32): h1 [B,256] | c1 [B,256] | hhat1 [B,128] | chat1 [B,128]

typedef unsigned short u16;
typedef __attribute__((ext_vector_type(8))) short bf16x8;   // 8 bf16 (4 VGPRs)
typedef __attribute__((ext_vector_type(4))) float f32x4;

#define BATCH 65536

__device__ __forceinline__ u16 f2b(float f) {           // f32 -> bf16 bits, RNE
  unsigned u = __float_as_uint(f);
  u += 0x7fffu + ((u >> 16) & 1u);
  return (u16)(u >> 16);
}
__device__ __forceinline__ unsigned pk2(float a, float b) {   // 2xf32 -> packed bf16
  return (unsigned)f2b(a) | ((unsigned)f2b(b) << 16);
}
__device__ __forceinline__ float upk_lo(unsigned u) { return __uint_as_float(u << 16); }
__device__ __forceinline__ float upk_hi(unsigned u) { return __uint_as_float(u & 0xffff0000u); }
__device__ __forceinline__ float sigf(float x) { return 1.0f / (1.0f + __expf(-x)); }
__device__ __forceinline__ float tanhfast(float x) {    // clamped exp-based tanh
  float xc = fminf(fmaxf(x, -15.f), 15.f);
  float e = __expf(2.f * xc);
  return (e - 1.f) / (e + 1.f);
}
// LDS XOR swizzle for [row][64] bf16 A-tiles (G4).
__device__ __forceinline__ int swz(int r, int c) { return r * 64 + (c ^ ((r & 7) << 3)); }

// counted-vmcnt barrier (T4) + scheduler fence (rule #18)
#define VM_BAR(N) do { \
  asm volatile("s_waitcnt vmcnt(" #N ")" ::: "memory"); \
  __builtin_amdgcn_s_barrier(); \
  __builtin_amdgcn_sched_barrier(0); } while (0)

// async global->LDS, 16B per lane (m97: global_load_lds_dwordx4)
__device__ __forceinline__ void gl_lds16(const u16* g, u16* l) {
  __builtin_amdgcn_global_load_lds(
      (const __attribute__((address_space(1))) void*)g,
      (__attribute__((address_space(3))) void*)l, 16, 0, 0);
}
// stage 64x64 A-tile (8 KB) from row-major bf16 (stride ldk) into the swizzled
// LDS image: linear LDS dest + XOR-permuted GLOBAL source chunks (m173).
__device__ __forceinline__ void stageA(const u16* base, int ldk, u16* lA, int t) {
  const int r = t >> 3, q = t & 7, wid = t >> 6;
  const int qs = (q ^ (r & 7)) << 3;                 // (r+32)&7 == r&7
  gl_lds16(base + (size_t)r * ldk + qs, lA + wid * 512);
  gl_lds16(base + (size_t)(r + 32) * ldk + qs, lA + 2048 + wid * 512);
}

// ---------------------------------------------------------------------------
// pre: fused input-cast + weight prep (fragment-major B).  [r10/r15, unchanged]
// ---------------------------------------------------------------------------
__global__ __launch_bounds__(256) void hlstm_pre(
    const float* __restrict__ hhat0, const float* __restrict__ h0,
    const float* __restrict__ x, u16* __restrict__ abuf,
    const float* __restrict__ hweight, const float* __restrict__ hbias,
    const float* __restrict__ zw_h, const float* __restrict__ zw_x, const float* __restrict__ zw_b,
    const float* __restrict__ zb_h, const float* __restrict__ zb_x,
    const float* __restrict__ dw_h, const float* __restrict__ dw_x, const float* __restrict__ dw_b,
    const float* __restrict__ weight, const float* __restrict__ bias,
    u16* __restrict__ hw_fr, float* __restrict__ hbias_r,
    u16* __restrict__ w_fr,  float* __restrict__ bias_r,
    u16* __restrict__ whp_fr, u16* __restrict__ wxp_fr, u16* __restrict__ wbp_fr,
    float* __restrict__ bhp_r, float* __restrict__ bxp_r)
{
  if (blockIdx.x < 4096) {
    // ---- cast part: abuf[B][512] = bf16([hhat0 | h0 | x])
    const size_t stride = (size_t)4096 * 256;
    for (size_t i = (size_t)blockIdx.x * 256 + threadIdx.x;
         i < (size_t)BATCH * 64; i += stride) {
      const size_t b = i >> 6; const int c = (int)(i & 63);
      const float* src;
      if (c < 16)      src = hhat0 + b * 128 + c * 8;
      else if (c < 48) src = h0 + b * 256 + (size_t)(c - 16) * 8;
      else             src = x + b * 128 + (size_t)(c - 48) * 8;
      float4 v0 = ((const float4*)src)[0];
      float4 v1 = ((const float4*)src)[1];
      alignas(16) u16 o[8] = {f2b(v0.x), f2b(v0.y), f2b(v0.z), f2b(v0.w),
                              f2b(v1.x), f2b(v1.y), f2b(v1.z), f2b(v1.w)};
      *(uint4*)(abuf + i * 8) = *(const uint4*)o;
    }
    return;
  }
  // ---- prep part: fragment-major images.
  const int tid = (blockIdx.x - 4096) * 256 + threadIdx.x;
  const int nt  = 512 * 256;

  // hw_fr: 16 tiles (hb*8+s), phys col = g*128 + hb*64 + hh
  for (int i = tid; i < 16 * 16384; i += nt) {
    int tile = i >> 14, r = i & 16383;
    int wc = r >> 12, h = (r >> 11) & 1, g = (r >> 9) & 3;
    int lane = (r >> 3) & 63, j = r & 7;
    int hb = tile >> 3, s = tile & 7;
    int k = s * 64 + h * 32 + (lane >> 4) * 8 + j;
    int col = g * 128 + hb * 64 + wc * 16 + (lane & 15);
    hw_fr[i] = f2b(hweight[k * 512 + col]);
  }
  // w_fr: 24 tiles (hb*6+s), phys col = g*256 + hb*64 + hh
  for (int i = tid; i < 24 * 16384; i += nt) {
    int tile = i >> 14, r = i & 16383;
    int wc = r >> 12, h = (r >> 11) & 1, g = (r >> 9) & 3;
    int lane = (r >> 3) & 63, j = r & 7;
    int hb = tile / 6, s = tile % 6;
    int k = s * 64 + h * 32 + (lane >> 4) * 8 + j;
    int col = g * 256 + hb * 64 + wc * 16 + (lane & 15);
    w_fr[i] = f2b(weight[k * 1024 + col]);
  }
  // folded hyper fragments: 3 mats x 8 tiles (hb*2+s); W'[k][(g,h)] = sum_e zw*dw
  for (int i = tid; i < 3 * 8 * 16384; i += nt) {
    int mat = i / (8 * 16384), rem = i % (8 * 16384);
    int tile = rem >> 14, r = rem & 16383;
    int wc = r >> 12, h = (r >> 11) & 1, g = (r >> 9) & 3;
    int lane = (r >> 3) & 63, j = r & 7;
    int hb = tile >> 1, s = tile & 1;
    int k = s * 64 + h * 32 + (lane >> 4) * 8 + j;       // 0..127
    int colh = hb * 64 + wc * 16 + (lane & 15);
    const float* zw = (mat == 0) ? zw_h : (mat == 1) ? zw_x : zw_b;
    const float* dw = (mat == 0) ? dw_h : (mat == 1) ? dw_x : dw_b;
    float sv = 0.f;
#pragma unroll
    for (int e = 0; e < 16; ++e)
      sv += zw[k * 64 + g * 16 + e] * dw[g * 4096 + e * 256 + colh];
    u16* dst = (mat == 0) ? whp_fr : (mat == 1) ? wxp_fr : wbp_fr;
    dst[rem] = f2b(sv);
  }
  // bias folds (virtual order hb*256 + g*64 + hh)
  for (int i = tid; i < 1024; i += nt) {
    int hb = i >> 8, g = (i >> 6) & 3, hh = i & 63;
    int h = hb * 64 + hh;
    float sh = 0.f, sx = 0.f;
#pragma unroll
    for (int e = 0; e < 16; ++e) {
      sh += zb_h[g * 16 + e] * dw_h[g * 4096 + e * 256 + h];
      sx += zb_x[g * 16 + e] * dw_x[g * 4096 + e * 256 + h];
    }
    bhp_r[i] = sh; bxp_r[i] = sx;
    bias_r[i] = bias[g * 256 + h];
  }
  for (int i = tid; i < 512; i += nt) {
    int gate = (i >> 6) & 3, hb = i >> 8, hh = i & 63;
    hbias_r[i] = hbias[gate * 128 + hb * 64 + hh];
  }
}

// ---------------------------------------------------------------------------
// k1: hyper GEMM (K=512, 8 steps) + hyper LSTM. 2048 blocks x 256 threads.
// A: LDS ring-3 (24 KB); B: single-buffered register fragments. [r15, unchanged]
// ---------------------------------------------------------------------------
__global__ __launch_bounds__(256, 3) void hlstm_k1(
    const u16* __restrict__ abuf, const float* __restrict__ chat0,
    const u16* __restrict__ hw_fr, const float* __restrict__ hbias_r,
    float* __restrict__ d_out, u16* __restrict__ hbuf)
{
  __shared__ alignas(16) u16 lA[3][64 * 64];
  const int f = blockIdx.x;                 // 0..2047
  const int xcd = f & 7, s2 = f >> 3;
  const int rb = xcd * 128 + (s2 >> 1), hb = s2 & 1;
  const int t = threadIdx.x;
  const int lane = t & 63, wc = t >> 6;
  const int lr = lane & 15, kg = lane >> 4;

  f32x4 acc[4][4];
  const f32x4 zzero = {0.f, 0.f, 0.f, 0.f};
#pragma unroll
  for (int mf = 0; mf < 4; ++mf)
#pragma unroll
    for (int g = 0; g < 4; ++g) acc[mf][g] = zzero;

  const u16* arow = abuf + (size_t)rb * 64 * 512;

  bf16x8 breg[8];
  auto loadB = [&](const u16* bt) {
#pragma unroll
    for (int h = 0; h < 2; ++h)
#pragma unroll
      for (int g = 0; g < 4; ++g)
        breg[h * 4 + g] = *(const bf16x8*)&bt[((wc * 2 + h) * 4 + g) * 512 + lane * 8];
  };
  auto sweep = [&](f32x4 (&ac)[4][4], const u16* cA) {
    __builtin_amdgcn_s_setprio(1);
#pragma unroll
    for (int h = 0; h < 2; ++h)
#pragma unroll
      for (int mf = 0; mf < 4; ++mf) {
        bf16x8 afr = *(const bf16x8*)&cA[swz(mf * 16 + lr, h * 32 + kg * 8)];
#pragma unroll
        for (int g = 0; g < 4; ++g)
          ac[mf][g] = __builtin_amdgcn_mfma_f32_16x16x32_bf16(afr, breg[h * 4 + g], ac[mf][g], 0, 0, 0);
      }
    __builtin_amdgcn_s_setprio(0);
  };

  // prologue: A(0), A(1) staged; B(0) issued. vmcnt(8) -> A done, B(0) rides.
  stageA(arow + 0 * 64, 512, lA[0], t);
  stageA(arow + 1 * 64, 512, lA[1], t);
  loadB(hw_fr + (size_t)(hb * 8 + 0) * 16384);
  VM_BAR(8);

#pragma unroll
  for (int ks = 0; ks < 8; ++ks) {
    if (ks < 6) stageA(arow + (ks + 2) * 64, 512, lA[(ks + 2) % 3], t);
    sweep(acc, lA[ks % 3]);                 // waits on breg (B(ks)) via compiler
    if (ks < 7) loadB(hw_fr + (size_t)(hb * 8 + ks + 1) * 16384);
    if (ks < 6)       VM_BAR(10);           // A(ks+2):2 + B(ks+1):8 in flight
    else if (ks == 6) VM_BAR(8);            // B(7):8 in flight
  }

  float hb4[4];
#pragma unroll
  for (int g = 0; g < 4; ++g) hb4[g] = hbias_r[hb * 256 + g * 64 + wc * 16 + lr];
  const int zc = hb * 64 + wc * 16 + lr;
  float* out_hh = d_out + (size_t)BATCH * 512;
  float* out_ch = d_out + (size_t)BATCH * 640;
#pragma unroll
  for (int mf = 0; mf < 4; ++mf)
#pragma unroll
    for (int r = 0; r < 4; ++r) {
      const int row = rb * 64 + mf * 16 + kg * 4 + r;
      const float gi = acc[mf][0][r] + hb4[0];
      const float gg = acc[mf][1][r] + hb4[1];
      const float gf = acc[mf][2][r] + hb4[2];
      const float go = acc[mf][3][r] + hb4[3];
      const float c0v = chat0[(size_t)row * 128 + zc];
      const float c1v = sigf(gf) * c0v + sigf(gi) * tanhfast(gg);
      const float h1v = sigf(go) * tanhfast(c1v);
      out_hh[(size_t)row * 128 + zc] = h1v;
      out_ch[(size_t)row * 128 + zc] = c1v;
      hbuf[(size_t)row * 128 + zc] = f2b(h1v);
    }
}

// ---------------------------------------------------------------------------
// k2: hyper-first 12 K-steps (s0-1 d_yh -> dsc ; s2-3 d_yx -> dsc ; s4-9 main
// gpre ; s9 acc*=dsc ; s10-11 d_yb MFMA C-in). 4096 blocks x 256 threads.
// A: LDS ring-2 with content-reuse skip at steps 2,3; B: reg fragments;
// dsc in per-thread LDS slots. LDS 48 KB -> 3 blocks/CU; (256,3).
// ---------------------------------------------------------------------------
__global__ __launch_bounds__(256, 3) void hlstm_k2(
    const u16* __restrict__ abuf, const u16* __restrict__ hbuf,
    const float* __restrict__ c0,
    const u16* __restrict__ w_fr, const float* __restrict__ bias_r,
    const u16* __restrict__ whp_fr, const u16* __restrict__ wxp_fr, const u16* __restrict__ wbp_fr,
    const float* __restrict__ bhp_r, const float* __restrict__ bxp_r,
    float* __restrict__ d_out)
{
  __shared__ alignas(16) u16 lA[2][64 * 64];     // 16 KB (ring-2)
  __shared__ alignas(16) unsigned ldsc[8192];    // 32 KB packed dscale
  const int f = blockIdx.x;                 // 0..4095
  const int xcd = f & 7, s4 = f >> 3;
  const int rb = xcd * 128 + (s4 >> 2), hb = s4 & 3;
  const int t = threadIdx.x;
  const int lane = t & 63, wc = t >> 6;
  const int lr = lane & 15, kg = lane >> 4;

  const u16* amain = abuf + (size_t)rb * 64 * 512 + 128;   // [h0|x] cols, ld 512
  const u16* ahyp  = hbuf + (size_t)rb * 64 * 128;         // ld 128

  // steps: 0..3 hyper (Wh',Wx'), 4..9 main, 10..11 hyper (Wb')
  auto aptr = [&](int s) -> const u16* {
    if (s >= 4 && s < 10) return amain + (s - 4) * 64;
    return ahyp + (s & 1) * 64;
  };
  auto aldk = [&](int s) -> int { return (s >= 4 && s < 10) ? 512 : 128; };
  auto bptr = [&](int s) -> const u16* {
    if (s < 2)  return whp_fr + (size_t)(hb * 2 + s) * 16384;
    if (s < 4)  return wxp_fr + (size_t)(hb * 2 + s - 2) * 16384;
    if (s < 10) return w_fr  + (size_t)(hb * 6 + s - 4) * 16384;
    return wbp_fr + (size_t)(hb * 2 + s - 10) * 16384;
  };

  f32x4 acc[4][4];
  const f32x4 zzero = {0.f, 0.f, 0.f, 0.f};
#pragma unroll
  for (int mf = 0; mf < 4; ++mf)
#pragma unroll
    for (int g = 0; g < 4; ++g) acc[mf][g] = zzero;

  bf16x8 breg[8];
  auto loadB = [&](const u16* bt) {
#pragma unroll
    for (int h = 0; h < 2; ++h)
#pragma unroll
      for (int g = 0; g < 4; ++g)
        breg[h * 4 + g] = *(const bf16x8*)&bt[((wc * 2 + h) * 4 + g) * 512 + lane * 8];
  };
  auto sweep = [&](f32x4 (&ac)[4][4], const u16* cA) {
    __builtin_amdgcn_s_setprio(1);
#pragma unroll
    for (int h = 0; h < 2; ++h)
#pragma unroll
      for (int mf = 0; mf < 4; ++mf) {
        bf16x8 afr = *(const bf16x8*)&cA[swz(mf * 16 + lr, h * 32 + kg * 8)];
#pragma unroll
        for (int g = 0; g < 4; ++g)
          ac[mf][g] = __builtin_amdgcn_mfma_f32_16x16x32_bf16(afr, breg[h * 4 + g], ac[mf][g], 0, 0, 0);
      }
    __builtin_amdgcn_s_setprio(0);
  };

  // prologue: A(0)->lA0, A(1)->lA1 staged; B(0) issued.
  stageA(aptr(0), aldk(0), lA[0], t);
  stageA(aptr(1), aldk(1), lA[1], t);
  loadB(bptr(0));
  VM_BAR(8);

#pragma unroll
  for (int s = 0; s < 12; ++s) {
    // stage(s+1): steps 1..3 need no stage (A(1) prologue-staged; A(2),A(3)
    // content-identical to A(0),A(1) in the same ring-2 buffers).
    if (s >= 3 && s < 11) stageA(aptr(s + 1), aldk(s + 1), lA[(s + 1) & 1], t);
    if (s == 2 || s == 4) {                 // new phase: re-zero single acc
#pragma unroll
      for (int mf = 0; mf < 4; ++mf)
#pragma unroll
        for (int g = 0; g < 4; ++g) acc[mf][g] = zzero;
    }
    sweep(acc, lA[s & 1]);                  // waits on breg (B(s)) via compiler
    if (s < 11) loadB(bptr(s + 1));

    if (s == 1) {                           // ldsc = pack(d_yh + bh')
      float bh4[4];
#pragma unroll
      for (int g = 0; g < 4; ++g) bh4[g] = bhp_r[hb * 256 + g * 64 + wc * 16 + lr];
#pragma unroll
      for (int mf = 0; mf < 4; ++mf)
#pragma unroll
        for (int gp = 0; gp < 2; ++gp) {
          const int g0 = gp * 2, g1 = gp * 2 + 1;
          uint4 v;
          v.x = pk2(acc[mf][g0][0] + bh4[g0], acc[mf][g0][1] + bh4[g0]);
          v.y = pk2(acc[mf][g0][2] + bh4[g0], acc[mf][g0][3] + bh4[g0]);
          v.z = pk2(acc[mf][g1][0] + bh4[g1], acc[mf][g1][1] + bh4[g1]);
          v.w = pk2(acc[mf][g1][2] + bh4[g1], acc[mf][g1][3] + bh4[g1]);
          *(uint4*)&ldsc[(mf * 2 + gp) * 1024 + t * 4] = v;
        }
    } else if (s == 3) {                    // ldsc *= (d_yx + bx')
      float bx4[4];
#pragma unroll
      for (int g = 0; g < 4; ++g) bx4[g] = bxp_r[hb * 256 + g * 64 + wc * 16 + lr];
#pragma unroll
      for (int mf = 0; mf < 4; ++mf)
#pragma unroll
        for (int gp = 0; gp < 2; ++gp) {
          const int g0 = gp * 2, g1 = gp * 2 + 1;
          uint4 v = *(const uint4*)&ldsc[(mf * 2 + gp) * 1024 + t * 4];
          v.x = pk2(upk_lo(v.x) * (acc[mf][g0][0] + bx4[g0]),
                    upk_hi(v.x) * (acc[mf][g0][1] + bx4[g0]));
          v.y = pk2(upk_lo(v.y) * (acc[mf][g0][2] + bx4[g0]),
                    upk_hi(v.y) * (acc[mf][g0][3] + bx4[g0]));
          v.z = pk2(upk_lo(v.z) * (acc[mf][g1][0] + bx4[g1]),
                    upk_hi(v.z) * (acc[mf][g1][1] + bx4[g1]));
          v.w = pk2(upk_lo(v.w) * (acc[mf][g1][2] + bx4[g1]),
                    upk_hi(v.w) * (acc[mf][g1][3] + bx4[g1]));
          *(uint4*)&ldsc[(mf * 2 + gp) * 1024 + t * 4] = v;
        }
    } else if (s == 9) {                    // acc(gpre) *= dscale
#pragma unroll
      for (int mf = 0; mf < 4; ++mf)
#pragma unroll
        for (int gp = 0; gp < 2; ++gp) {
          const int g0 = gp * 2, g1 = gp * 2 + 1;
          uint4 v = *(const uint4*)&ldsc[(mf * 2 + gp) * 1024 + t * 4];
          acc[mf][g0][0] *= upk_lo(v.x);
          acc[mf][g0][1] *= upk_hi(v.x);
          acc[mf][g0][2] *= upk_lo(v.y);
          acc[mf][g0][3] *= upk_hi(v.y);
          acc[mf][g1][0] *= upk_lo(v.z);
          acc[mf][g1][1] *= upk_hi(v.z);
          acc[mf][g1][2] *= upk_lo(v.w);
          acc[mf][g1][3] *= upk_hi(v.w);
        }
    }
    if (s < 11) VM_BAR(8);                  // forces stageA(s+1) when staged
  }

  // ---- epilogue: main LSTM cell (acc = gpre*dscale + d_yb)
  const int hcol = hb * 64 + wc * 16 + lr;
  float b4[4];
#pragma unroll
  for (int g = 0; g < 4; ++g) b4[g] = bias_r[hb * 256 + g * 64 + wc * 16 + lr];
  float* out_c1 = d_out + (size_t)BATCH * 256;
#pragma unroll
  for (int mf = 0; mf < 4; ++mf)
#pragma unroll
    for (int r = 0; r < 4; ++r) {
      const int row = rb * 64 + mf * 16 + kg * 4 + r;
      const float gi = acc[mf][0][r] + b4[0];
      const float gg = acc[mf][1][r] + b4[1];
      const float gf = acc[mf][2][r] + b4[2];
      const float go = acc[mf][3][r] + b4[3];
      const float c0v = c0[(size_t)row * 256 + hcol];
      const float c1v = sigf(gf) * c0v + sigf(gi) * tanhfast(gg);
      const float h1v = sigf(go) * tanhfast(c1v);
      d_out[(size_t)row * 256 + hcol]  = h1v;
      out_c1[(size_t)row * 256 + hcol] = c1v;
    }
}

// ---------------------------------------------------------------------------
extern "C" void kernel_launch(void* const* d_in, const int* in_sizes, int n_in,
                              void* d_out, int out_size, void* d_ws, size_t ws_size,
                              hipStream_t stream)
{
  (void)in_sizes; (void)n_in; (void)out_size; (void)ws_size;
  const float* x       = (const float*)d_in[0];
  const float* h0      = (const float*)d_in[1];
  const float* c0      = (const float*)d_in[2];
  const float* hhat0   = (const float*)d_in[3];
  const float* chat0   = (const float*)d_in[4];
  const float* hweight = (const float*)d_in[5];
  const float* hbias   = (const float*)d_in[6];
  const float* zw_h    = (const float*)d_in[7];
  const float* zw_x    = (const float*)d_in[8];
  const float* zw_b    = (const float*)d_in[9];
  const float* zb_h    = (const float*)d_in[10];
  const float* zb_x    = (const float*)d_in[11];
  const float* dw_h    = (const float*)d_in[12];
  const float* dw_x    = (const float*)d_in[13];
  const float* dw_b    = (const float*)d_in[14];
  const float* weight  = (const float*)d_in[15];
  const float* bias    = (const float*)d_in[16];

  // workspace layout (bytes, 16B-aligned); total ~86 MB
  char* wsb = (char*)d_ws;
  u16*   abuf    = (u16*)(wsb + 0);              // B*512*2   = 67108864
  u16*   hbuf    = (u16*)(wsb + 67108864);       // B*128*2   = 16777216
  u16*   hw_fr   = (u16*)(wsb + 83886080);       // 16*16384*2 = 524288
  u16*   w_fr    = (u16*)(wsb + 84410368);       // 24*16384*2 = 786432
  u16*   whp_fr  = (u16*)(wsb + 85196800);       // 8*16384*2  = 262144
  u16*   wxp_fr  = (u16*)(wsb + 85458944);
  u16*   wbp_fr  = (u16*)(wsb + 85721088);
  float* hbias_r = (float*)(wsb + 85983232);     // 512*4
  float* bias_r  = (float*)(wsb + 85985280);     // 1024*4
  float* bhp_r   = (float*)(wsb + 85989376);     // 1024*4
  float* bxp_r   = (float*)(wsb + 85993472);     // 1024*4

  hlstm_pre<<<dim3(4608), dim3(256), 0, stream>>>(
      hhat0, h0, x, abuf,
      hweight, hbias, zw_h, zw_x, zw_b, zb_h, zb_x, dw_h, dw_x, dw_b, weight, bias,
      hw_fr, hbias_r, w_fr, bias_r, whp_fr, wxp_fr, wbp_fr, bhp_r, bxp_r);

  hlstm_k1<<<dim3(2048), dim3(256), 0, stream>>>(
      abuf, chat0, hw_fr, hbias_r, (float*)d_out, hbuf);

  hlstm_k2<<<dim3(4096), dim3(256), 0, stream>>>(
      abuf, hbuf, c0, w_fr, bias_r, whp_fr, wxp_fr, wbp_fr, bhp_r, bxp_r, (float*)d_out);
}

// Round 19
// 259.758 us; speedup vs baseline: 1.2632x; 1.0176x over previous
//
#include <hip/hip_runtime.h>

// HyperLSTMCell on MI355X (gfx950).  B=65536, D=128, H=256, Z=128, E=16.
// All inputs/outputs f32; internal GEMMs bf16 MFMA (16x16x32).
//
// r19 = r17 verbatim (proven best: 264.3 us total, clean counters, stable
// under graph replay). r16 (half-split B + prefetch: 150 MB spill) and
// r18 (half-split B alone: post-timing race in k1's hhat1) are both
// REVERTED — the B-latency micro-optimization is correctness-negative in
// this register-capped regime.
//
// Structure: 3 waves/SIMD (dsc-in-LDS + __launch_bounds__(256,3), 48 KB LDS
// -> 3 blocks/CU); A via LDS ring (ring-3 k1 / ring-2 k2 with content-reuse
// skip at s2,s3); B single-buffered register fragments (fragment-major
// images); counted-vmcnt barriers (never drain mid-loop); setprio around
// MFMA clusters; XCD sibling swizzle on blockIdx.
//
// d_out (f32): h1 [B,256] | c1 [B,256] | hhat1 [B,128] | chat1 [B,128]

typedef unsigned short u16;
typedef __attribute__((ext_vector_type(8))) short bf16x8;   // 8 bf16 (4 VGPRs)
typedef __attribute__((ext_vector_type(4))) float f32x4;

#define BATCH 65536

__device__ __forceinline__ u16 f2b(float f) {           // f32 -> bf16 bits, RNE
  unsigned u = __float_as_uint(f);
  u += 0x7fffu + ((u >> 16) & 1u);
  return (u16)(u >> 16);
}
__device__ __forceinline__ unsigned pk2(float a, float b) {   // 2xf32 -> packed bf16
  return (unsigned)f2b(a) | ((unsigned)f2b(b) << 16);
}
__device__ __forceinline__ float upk_lo(unsigned u) { return __uint_as_float(u << 16); }
__device__ __forceinline__ float upk_hi(unsigned u) { return __uint_as_float(u & 0xffff0000u); }
__device__ __forceinline__ float sigf(float x) { return 1.0f / (1.0f + __expf(-x)); }
__device__ __forceinline__ float tanhfast(float x) {    // clamped exp-based tanh
  float xc = fminf(fmaxf(x, -15.f), 15.f);
  float e = __expf(2.f * xc);
  return (e - 1.f) / (e + 1.f);
}
// LDS XOR swizzle for [row][64] bf16 A-tiles (G4).
__device__ __forceinline__ int swz(int r, int c) { return r * 64 + (c ^ ((r & 7) << 3)); }

// counted-vmcnt barrier (T4) + scheduler fence (rule #18)
#define VM_BAR(N) do { \
  asm volatile("s_waitcnt vmcnt(" #N ")" ::: "memory"); \
  __builtin_amdgcn_s_barrier(); \
  __builtin_amdgcn_sched_barrier(0); } while (0)

// async global->LDS, 16B per lane (m97: global_load_lds_dwordx4)
__device__ __forceinline__ void gl_lds16(const u16* g, u16* l) {
  __builtin_amdgcn_global_load_lds(
      (const __attribute__((address_space(1))) void*)g,
      (__attribute__((address_space(3))) void*)l, 16, 0, 0);
}
// stage 64x64 A-tile (8 KB) from row-major bf16 (stride ldk) into the swizzled
// LDS image: linear LDS dest + XOR-permuted GLOBAL source chunks (m173).
__device__ __forceinline__ void stageA(const u16* base, int ldk, u16* lA, int t) {
  const int r = t >> 3, q = t & 7, wid = t >> 6;
  const int qs = (q ^ (r & 7)) << 3;                 // (r+32)&7 == r&7
  gl_lds16(base + (size_t)r * ldk + qs, lA + wid * 512);
  gl_lds16(base + (size_t)(r + 32) * ldk + qs, lA + 2048 + wid * 512);
}

// ---------------------------------------------------------------------------
// pre: fused input-cast + weight prep (fragment-major B).
// ---------------------------------------------------------------------------
__global__ __launch_bounds__(256) void hlstm_pre(
    const float* __restrict__ hhat0, const float* __restrict__ h0,
    const float* __restrict__ x, u16* __restrict__ abuf,
    const float* __restrict__ hweight, const float* __restrict__ hbias,
    const float* __restrict__ zw_h, const float* __restrict__ zw_x, const float* __restrict__ zw_b,
    const float* __restrict__ zb_h, const float* __restrict__ zb_x,
    const float* __restrict__ dw_h, const float* __restrict__ dw_x, const float* __restrict__ dw_b,
    const float* __restrict__ weight, const float* __restrict__ bias,
    u16* __restrict__ hw_fr, float* __restrict__ hbias_r,
    u16* __restrict__ w_fr,  float* __restrict__ bias_r,
    u16* __restrict__ whp_fr, u16* __restrict__ wxp_fr, u16* __restrict__ wbp_fr,
    float* __restrict__ bhp_r, float* __restrict__ bxp_r)
{
  if (blockIdx.x < 4096) {
    // ---- cast part: abuf[B][512] = bf16([hhat0 | h0 | x])
    const size_t stride = (size_t)4096 * 256;
    for (size_t i = (size_t)blockIdx.x * 256 + threadIdx.x;
         i < (size_t)BATCH * 64; i += stride) {
      const size_t b = i >> 6; const int c = (int)(i & 63);
      const float* src;
      if (c < 16)      src = hhat0 + b * 128 + c * 8;
      else if (c < 48) src = h0 + b * 256 + (size_t)(c - 16) * 8;
      else             src = x + b * 128 + (size_t)(c - 48) * 8;
      float4 v0 = ((const float4*)src)[0];
      float4 v1 = ((const float4*)src)[1];
      alignas(16) u16 o[8] = {f2b(v0.x), f2b(v0.y), f2b(v0.z), f2b(v0.w),
                              f2b(v1.x), f2b(v1.y), f2b(v1.z), f2b(v1.w)};
      *(uint4*)(abuf + i * 8) = *(const uint4*)o;
    }
    return;
  }
  // ---- prep part: fragment-major images.
  const int tid = (blockIdx.x - 4096) * 256 + threadIdx.x;
  const int nt  = 512 * 256;

  // hw_fr: 16 tiles (hb*8+s), phys col = g*128 + hb*64 + hh
  for (int i = tid; i < 16 * 16384; i += nt) {
    int tile = i >> 14, r = i & 16383;
    int wc = r >> 12, h = (r >> 11) & 1, g = (r >> 9) & 3;
    int lane = (r >> 3) & 63, j = r & 7;
    int hb = tile >> 3, s = tile & 7;
    int k = s * 64 + h * 32 + (lane >> 4) * 8 + j;
    int col = g * 128 + hb * 64 + wc * 16 + (lane & 15);
    hw_fr[i] = f2b(hweight[k * 512 + col]);
  }
  // w_fr: 24 tiles (hb*6+s), phys col = g*256 + hb*64 + hh
  for (int i = tid; i < 24 * 16384; i += nt) {
    int tile = i >> 14, r = i & 16383;
    int wc = r >> 12, h = (r >> 11) & 1, g = (r >> 9) & 3;
    int lane = (r >> 3) & 63, j = r & 7;
    int hb = tile / 6, s = tile % 6;
    int k = s * 64 + h * 32 + (lane >> 4) * 8 + j;
    int col = g * 256 + hb * 64 + wc * 16 + (lane & 15);
    w_fr[i] = f2b(weight[k * 1024 + col]);
  }
  // folded hyper fragments: 3 mats x 8 tiles (hb*2+s); W'[k][(g,h)] = sum_e zw*dw
  for (int i = tid; i < 3 * 8 * 16384; i += nt) {
    int mat = i / (8 * 16384), rem = i % (8 * 16384);
    int tile = rem >> 14, r = rem & 16383;
    int wc = r >> 12, h = (r >> 11) & 1, g = (r >> 9) & 3;
    int lane = (r >> 3) & 63, j = r & 7;
    int hb = tile >> 1, s = tile & 1;
    int k = s * 64 + h * 32 + (lane >> 4) * 8 + j;       // 0..127
    int colh = hb * 64 + wc * 16 + (lane & 15);
    const float* zw = (mat == 0) ? zw_h : (mat == 1) ? zw_x : zw_b;
    const float* dw = (mat == 0) ? dw_h : (mat == 1) ? dw_x : dw_b;
    float sv = 0.f;
#pragma unroll
    for (int e = 0; e < 16; ++e)
      sv += zw[k * 64 + g * 16 + e] * dw[g * 4096 + e * 256 + colh];
    u16* dst = (mat == 0) ? whp_fr : (mat == 1) ? wxp_fr : wbp_fr;
    dst[rem] = f2b(sv);
  }
  // bias folds (virtual order hb*256 + g*64 + hh)
  for (int i = tid; i < 1024; i += nt) {
    int hb = i >> 8, g = (i >> 6) & 3, hh = i & 63;
    int h = hb * 64 + hh;
    float sh = 0.f, sx = 0.f;
#pragma unroll
    for (int e = 0; e < 16; ++e) {
      sh += zb_h[g * 16 + e] * dw_h[g * 4096 + e * 256 + h];
      sx += zb_x[g * 16 + e] * dw_x[g * 4096 + e * 256 + h];
    }
    bhp_r[i] = sh; bxp_r[i] = sx;
    bias_r[i] = bias[g * 256 + h];
  }
  for (int i = tid; i < 512; i += nt) {
    int gate = (i >> 6) & 3, hb = i >> 8, hh = i & 63;
    hbias_r[i] = hbias[gate * 128 + hb * 64 + hh];
  }
}

// ---------------------------------------------------------------------------
// k1: hyper GEMM (K=512, 8 steps) + hyper LSTM. 2048 blocks x 256 threads.
// A: LDS ring-3 (24 KB); B: single-buffered register fragments.
// ---------------------------------------------------------------------------
__global__ __launch_bounds__(256, 3) void hlstm_k1(
    const u16* __restrict__ abuf, const float* __restrict__ chat0,
    const u16* __restrict__ hw_fr, const float* __restrict__ hbias_r,
    float* __restrict__ d_out, u16* __restrict__ hbuf)
{
  __shared__ alignas(16) u16 lA[3][64 * 64];
  const int f = blockIdx.x;                 // 0..2047
  const int xcd = f & 7, s2 = f >> 3;
  const int rb = xcd * 128 + (s2 >> 1), hb = s2 & 1;
  const int t = threadIdx.x;
  const int lane = t & 63, wc = t >> 6;
  const int lr = lane & 15, kg = lane >> 4;

  f32x4 acc[4][4];
  const f32x4 zzero = {0.f, 0.f, 0.f, 0.f};
#pragma unroll
  for (int mf = 0; mf < 4; ++mf)
#pragma unroll
    for (int g = 0; g < 4; ++g) acc[mf][g] = zzero;

  const u16* arow = abuf + (size_t)rb * 64 * 512;

  bf16x8 breg[8];
  auto loadB = [&](const u16* bt) {
#pragma unroll
    for (int h = 0; h < 2; ++h)
#pragma unroll
      for (int g = 0; g < 4; ++g)
        breg[h * 4 + g] = *(const bf16x8*)&bt[((wc * 2 + h) * 4 + g) * 512 + lane * 8];
  };
  auto sweep = [&](f32x4 (&ac)[4][4], const u16* cA) {
    __builtin_amdgcn_s_setprio(1);
#pragma unroll
    for (int h = 0; h < 2; ++h)
#pragma unroll
      for (int mf = 0; mf < 4; ++mf) {
        bf16x8 afr = *(const bf16x8*)&cA[swz(mf * 16 + lr, h * 32 + kg * 8)];
#pragma unroll
        for (int g = 0; g < 4; ++g)
          ac[mf][g] = __builtin_amdgcn_mfma_f32_16x16x32_bf16(afr, breg[h * 4 + g], ac[mf][g], 0, 0, 0);
      }
    __builtin_amdgcn_s_setprio(0);
  };

  // prologue: A(0), A(1) staged; B(0) issued. vmcnt(8) -> A done, B(0) rides.
  stageA(arow + 0 * 64, 512, lA[0], t);
  stageA(arow + 1 * 64, 512, lA[1], t);
  loadB(hw_fr + (size_t)(hb * 8 + 0) * 16384);
  VM_BAR(8);

#pragma unroll
  for (int ks = 0; ks < 8; ++ks) {
    if (ks < 6) stageA(arow + (ks + 2) * 64, 512, lA[(ks + 2) % 3], t);
    sweep(acc, lA[ks % 3]);                 // waits on breg (B(ks)) via compiler
    if (ks < 7) loadB(hw_fr + (size_t)(hb * 8 + ks + 1) * 16384);
    if (ks < 6)       VM_BAR(10);           // A(ks+2):2 + B(ks+1):8 in flight
    else if (ks == 6) VM_BAR(8);            // B(7):8 in flight
  }

  float hb4[4];
#pragma unroll
  for (int g = 0; g < 4; ++g) hb4[g] = hbias_r[hb * 256 + g * 64 + wc * 16 + lr];
  const int zc = hb * 64 + wc * 16 + lr;
  float* out_hh = d_out + (size_t)BATCH * 512;
  float* out_ch = d_out + (size_t)BATCH * 640;
#pragma unroll
  for (int mf = 0; mf < 4; ++mf)
#pragma unroll
    for (int r = 0; r < 4; ++r) {
      const int row = rb * 64 + mf * 16 + kg * 4 + r;
      const float gi = acc[mf][0][r] + hb4[0];
      const float gg = acc[mf][1][r] + hb4[1];
      const float gf = acc[mf][2][r] + hb4[2];
      const float go = acc[mf][3][r] + hb4[3];
      const float c0v = chat0[(size_t)row * 128 + zc];
      const float c1v = sigf(gf) * c0v + sigf(gi) * tanhfast(gg);
      const float h1v = sigf(go) * tanhfast(c1v);
      out_hh[(size_t)row * 128 + zc] = h1v;
      out_ch[(size_t)row * 128 + zc] = c1v;
      hbuf[(size_t)row * 128 + zc] = f2b(h1v);
    }
}

// ---------------------------------------------------------------------------
// k2: hyper-first 12 K-steps (s0-1 d_yh -> dsc ; s2-3 d_yx -> dsc ; s4-9 main
// gpre ; s9 acc*=dsc ; s10-11 d_yb MFMA C-in). 4096 blocks x 256 threads.
// A: LDS ring-2 with content-reuse skip at steps 2,3; B: reg fragments;
// dsc in per-thread LDS slots. LDS 48 KB -> 3 blocks/CU; (256,3).
// ---------------------------------------------------------------------------
__global__ __launch_bounds__(256, 3) void hlstm_k2(
    const u16* __restrict__ abuf, const u16* __restrict__ hbuf,
    const float* __restrict__ c0,
    const u16* __restrict__ w_fr, const float* __restrict__ bias_r,
    const u16* __restrict__ whp_fr, const u16* __restrict__ wxp_fr, const u16* __restrict__ wbp_fr,
    const float* __restrict__ bhp_r, const float* __restrict__ bxp_r,
    float* __restrict__ d_out)
{
  __shared__ alignas(16) u16 lA[2][64 * 64];     // 16 KB (ring-2)
  __shared__ alignas(16) unsigned ldsc[8192];    // 32 KB packed dscale
  const int f = blockIdx.x;                 // 0..4095
  const int xcd = f & 7, s4 = f >> 3;
  const int rb = xcd * 128 + (s4 >> 2), hb = s4 & 3;
  const int t = threadIdx.x;
  const int lane = t & 63, wc = t >> 6;
  const int lr = lane & 15, kg = lane >> 4;

  const u16* amain = abuf + (size_t)rb * 64 * 512 + 128;   // [h0|x] cols, ld 512
  const u16* ahyp  = hbuf + (size_t)rb * 64 * 128;         // ld 128

  // steps: 0..3 hyper (Wh',Wx'), 4..9 main, 10..11 hyper (Wb')
  auto aptr = [&](int s) -> const u16* {
    if (s >= 4 && s < 10) return amain + (s - 4) * 64;
    return ahyp + (s & 1) * 64;
  };
  auto aldk = [&](int s) -> int { return (s >= 4 && s < 10) ? 512 : 128; };
  auto bptr = [&](int s) -> const u16* {
    if (s < 2)  return whp_fr + (size_t)(hb * 2 + s) * 16384;
    if (s < 4)  return wxp_fr + (size_t)(hb * 2 + s - 2) * 16384;
    if (s < 10) return w_fr  + (size_t)(hb * 6 + s - 4) * 16384;
    return wbp_fr + (size_t)(hb * 2 + s - 10) * 16384;
  };

  f32x4 acc[4][4];
  const f32x4 zzero = {0.f, 0.f, 0.f, 0.f};
#pragma unroll
  for (int mf = 0; mf < 4; ++mf)
#pragma unroll
    for (int g = 0; g < 4; ++g) acc[mf][g] = zzero;

  bf16x8 breg[8];
  auto loadB = [&](const u16* bt) {
#pragma unroll
    for (int h = 0; h < 2; ++h)
#pragma unroll
      for (int g = 0; g < 4; ++g)
        breg[h * 4 + g] = *(const bf16x8*)&bt[((wc * 2 + h) * 4 + g) * 512 + lane * 8];
  };
  auto sweep = [&](f32x4 (&ac)[4][4], const u16* cA) {
    __builtin_amdgcn_s_setprio(1);
#pragma unroll
    for (int h = 0; h < 2; ++h)
#pragma unroll
      for (int mf = 0; mf < 4; ++mf) {
        bf16x8 afr = *(const bf16x8*)&cA[swz(mf * 16 + lr, h * 32 + kg * 8)];
#pragma unroll
        for (int g = 0; g < 4; ++g)
          ac[mf][g] = __builtin_amdgcn_mfma_f32_16x16x32_bf16(afr, breg[h * 4 + g], ac[mf][g], 0, 0, 0);
      }
    __builtin_amdgcn_s_setprio(0);
  };

  // prologue: A(0)->lA0, A(1)->lA1 staged; B(0) issued.
  stageA(aptr(0), aldk(0), lA[0], t);
  stageA(aptr(1), aldk(1), lA[1], t);
  loadB(bptr(0));
  VM_BAR(8);

#pragma unroll
  for (int s = 0; s < 12; ++s) {
    // stage(s+1): steps 1..3 need no stage (A(1) prologue-staged; A(2),A(3)
    // content-identical to A(0),A(1) in the same ring-2 buffers).
    if (s >= 3 && s < 11) stageA(aptr(s + 1), aldk(s + 1), lA[(s + 1) & 1], t);
    if (s == 2 || s == 4) {                 // new phase: re-zero single acc
#pragma unroll
      for (int mf = 0; mf < 4; ++mf)
#pragma unroll
        for (int g = 0; g < 4; ++g) acc[mf][g] = zzero;
    }
    sweep(acc, lA[s & 1]);                  // waits on breg (B(s)) via compiler
    if (s < 11) loadB(bptr(s + 1));

    if (s == 1) {                           // ldsc = pack(d_yh + bh')
      float bh4[4];
#pragma unroll
      for (int g = 0; g < 4; ++g) bh4[g] = bhp_r[hb * 256 + g * 64 + wc * 16 + lr];
#pragma unroll
      for (int mf = 0; mf < 4; ++mf)
#pragma unroll
        for (int gp = 0; gp < 2; ++gp) {
          const int g0 = gp * 2, g1 = gp * 2 + 1;
          uint4 v;
          v.x = pk2(acc[mf][g0][0] + bh4[g0], acc[mf][g0][1] + bh4[g0]);
          v.y = pk2(acc[mf][g0][2] + bh4[g0], acc[mf][g0][3] + bh4[g0]);
          v.z = pk2(acc[mf][g1][0] + bh4[g1], acc[mf][g1][1] + bh4[g1]);
          v.w = pk2(acc[mf][g1][2] + bh4[g1], acc[mf][g1][3] + bh4[g1]);
          *(uint4*)&ldsc[(mf * 2 + gp) * 1024 + t * 4] = v;
        }
    } else if (s == 3) {                    // ldsc *= (d_yx + bx')
      float bx4[4];
#pragma unroll
      for (int g = 0; g < 4; ++g) bx4[g] = bxp_r[hb * 256 + g * 64 + wc * 16 + lr];
#pragma unroll
      for (int mf = 0; mf < 4; ++mf)
#pragma unroll
        for (int gp = 0; gp < 2; ++gp) {
          const int g0 = gp * 2, g1 = gp * 2 + 1;
          uint4 v = *(const uint4*)&ldsc[(mf * 2 + gp) * 1024 + t * 4];
          v.x = pk2(upk_lo(v.x) * (acc[mf][g0][0] + bx4[g0]),
                    upk_hi(v.x) * (acc[mf][g0][1] + bx4[g0]));
          v.y = pk2(upk_lo(v.y) * (acc[mf][g0][2] + bx4[g0]),
                    upk_hi(v.y) * (acc[mf][g0][3] + bx4[g0]));
          v.z = pk2(upk_lo(v.z) * (acc[mf][g1][0] + bx4[g1]),
                    upk_hi(v.z) * (acc[mf][g1][1] + bx4[g1]));
          v.w = pk2(upk_lo(v.w) * (acc[mf][g1][2] + bx4[g1]),
                    upk_hi(v.w) * (acc[mf][g1][3] + bx4[g1]));
          *(uint4*)&ldsc[(mf * 2 + gp) * 1024 + t * 4] = v;
        }
    } else if (s == 9) {                    // acc(gpre) *= dscale
#pragma unroll
      for (int mf = 0; mf < 4; ++mf)
#pragma unroll
        for (int gp = 0; gp < 2; ++gp) {
          const int g0 = gp * 2, g1 = gp * 2 + 1;
          uint4 v = *(const uint4*)&ldsc[(mf * 2 + gp) * 1024 + t * 4];
          acc[mf][g0][0] *= upk_lo(v.x);
          acc[mf][g0][1] *= upk_hi(v.x);
          acc[mf][g0][2] *= upk_lo(v.y);
          acc[mf][g0][3] *= upk_hi(v.y);
          acc[mf][g1][0] *= upk_lo(v.z);
          acc[mf][g1][1] *= upk_hi(v.z);
          acc[mf][g1][2] *= upk_lo(v.w);
          acc[mf][g1][3] *= upk_hi(v.w);
        }
    }
    if (s < 11) VM_BAR(8);                  // forces stageA(s+1) when staged
  }

  // ---- epilogue: main LSTM cell (acc = gpre*dscale + d_yb)
  const int hcol = hb * 64 + wc * 16 + lr;
  float b4[4];
#pragma unroll
  for (int g = 0; g < 4; ++g) b4[g] = bias_r[hb * 256 + g * 64 + wc * 16 + lr];
  float* out_c1 = d_out + (size_t)BATCH * 256;
#pragma unroll
  for (int mf = 0; mf < 4; ++mf)
#pragma unroll
    for (int r = 0; r < 4; ++r) {
      const int row = rb * 64 + mf * 16 + kg * 4 + r;
      const float gi = acc[mf][0][r] + b4[0];
      const float gg = acc[mf][1][r] + b4[1];
      const float gf = acc[mf][2][r] + b4[2];
      const float go = acc[mf][3][r] + b4[3];
      const float c0v = c0[(size_t)row * 256 + hcol];
      const float c1v = sigf(gf) * c0v + sigf(gi) * tanhfast(gg);
      const float h1v = sigf(go) * tanhfast(c1v);
      d_out[(size_t)row * 256 + hcol]  = h1v;
      out_c1[(size_t)row * 256 + hcol] = c1v;
    }
}

// ---------------------------------------------------------------------------
extern "C" void kernel_launch(void* const* d_in, const int* in_sizes, int n_in,
                              void* d_out, int out_size, void* d_ws, size_t ws_size,
                              hipStream_t stream)
{
  (void)in_sizes; (void)n_in; (void)out_size; (void)ws_size;
  const float* x       = (const float*)d_in[0];
  const float* h0      = (const float*)d_in[1];
  const float* c0      = (const float*)d_in[2];
  const float* hhat0   = (const float*)d_in[3];
  const float* chat0   = (const float*)d_in[4];
  const float* hweight = (const float*)d_in[5];
  const float* hbias   = (const float*)d_in[6];
  const float* zw_h    = (const float*)d_in[7];
  const float* zw_x    = (const float*)d_in[8];
  const float* zw_b    = (const float*)d_in[9];
  const float* zb_h    = (const float*)d_in[10];
  const float* zb_x    = (const float*)d_in[11];
  const float* dw_h    = (const float*)d_in[12];
  const float* dw_x    = (const float*)d_in[13];
  const float* dw_b    = (const float*)d_in[14];
  const float* weight  = (const float*)d_in[15];
  const float* bias    = (const float*)d_in[16];

  // workspace layout (bytes, 16B-aligned); total ~86 MB
  char* wsb = (char*)d_ws;
  u16*   abuf    = (u16*)(wsb + 0);              // B*512*2   = 67108864
  u16*   hbuf    = (u16*)(wsb + 67108864);       // B*128*2   = 16777216
  u16*   hw_fr   = (u16*)(wsb + 83886080);       // 16*16384*2 = 524288
  u16*   w_fr    = (u16*)(wsb + 84410368);       // 24*16384*2 = 786432
  u16*   whp_fr  = (u16*)(wsb + 85196800);       // 8*16384*2  = 262144
  u16*   wxp_fr  = (u16*)(wsb + 85458944);
  u16*   wbp_fr  = (u16*)(wsb + 85721088);
  float* hbias_r = (float*)(wsb + 85983232);     // 512*4
  float* bias_r  = (float*)(wsb + 85985280);     // 1024*4
  float* bhp_r   = (float*)(wsb + 85989376);     // 1024*4
  float* bxp_r   = (float*)(wsb + 85993472);     // 1024*4

  hlstm_pre<<<dim3(4608), dim3(256), 0, stream>>>(
      hhat0, h0, x, abuf,
      hweight, hbias, zw_h, zw_x, zw_b, zb_h, zb_x, dw_h, dw_x, dw_b, weight, bias,
      hw_fr, hbias_r, w_fr, bias_r, whp_fr, wxp_fr, wbp_fr, bhp_r, bxp_r);

  hlstm_k1<<<dim3(2048), dim3(256), 0, stream>>>(
      abuf, chat0, hw_fr, hbias_r, (float*)d_out, hbuf);

  hlstm_k2<<<dim3(4096), dim3(256), 0, stream>>>(
      abuf, hbuf, c0, w_fr, bias_r, whp_fr, wxp_fr, wbp_fr, bhp_r, bxp_r, (float*)d_out);
}

// Round 20
// 259.519 us; speedup vs baseline: 1.2644x; 1.0009x over previous
//
#include <hip/hip_runtime.h>

// HyperLSTMCell on MI355X (gfx950).  B=65536, D=128, H=256, Z=128, E=16.
// All inputs/outputs f32; internal GEMMs bf16 MFMA (16x16x32).
//
// FINAL (r20 = r17/r19 verbatim, best verified: ~260 us total, stable under
// graph replay, zero spill, zero bank conflicts).
//
// Pipeline:
//   pre: fused input cast ([hhat0|h0|x] -> bf16 abuf) + weight prep into
//        fragment-major bf16 images (gate-gathered virtual col order
//        v = hb*256 + gate*64 + hh) + algebraic fold of the embedding/einsum
//        chain: W'h = zw_h @ dw_h_blockdiag (dense 128x1024), bh' = zb_h @ ...,
//        same for x; W'b = zw_b @ dw_b_bd. Eliminates z/[B,4H] intermediates.
//   k1:  gh = abuf@hweight + hbias; hyper LSTM -> hhat1/chat1 (f32) + hbuf(bf16).
//   k2:  hyper-first 12 K-steps with ONE accumulator:
//        s0-1 d_yh -> dsc(packed bf16, LDS); s2-3 d_yx -> dsc; s4-9 gpre;
//        s9 acc*=dsc; s10-11 d_yb via MFMA C-in; fused LSTM epilogue.
//
// Structure: 3 waves/SIMD (dsc-in-LDS + __launch_bounds__(256,3); 48 KB LDS
// -> 3 blocks/CU); A via LDS ring (ring-3 k1 / ring-2 k2 + content-reuse skip
// at s2,s3); B single-buffered register fragments; counted-vmcnt barriers
// (never drain mid-loop); setprio around MFMA; XCD sibling swizzle.
//
// d_out (f32): h1 [B,256] | c1 [B,256] | hhat1 [B,128] | chat1 [B,128]

typedef unsigned short u16;
typedef __attribute__((ext_vector_type(8))) short bf16x8;   // 8 bf16 (4 VGPRs)
typedef __attribute__((ext_vector_type(4))) float f32x4;

#define BATCH 65536

__device__ __forceinline__ u16 f2b(float f) {           // f32 -> bf16 bits, RNE
  unsigned u = __float_as_uint(f);
  u += 0x7fffu + ((u >> 16) & 1u);
  return (u16)(u >> 16);
}
__device__ __forceinline__ unsigned pk2(float a, float b) {   // 2xf32 -> packed bf16
  return (unsigned)f2b(a) | ((unsigned)f2b(b) << 16);
}
__device__ __forceinline__ float upk_lo(unsigned u) { return __uint_as_float(u << 16); }
__device__ __forceinline__ float upk_hi(unsigned u) { return __uint_as_float(u & 0xffff0000u); }
__device__ __forceinline__ float sigf(float x) { return 1.0f / (1.0f + __expf(-x)); }
__device__ __forceinline__ float tanhfast(float x) {    // clamped exp-based tanh
  float xc = fminf(fmaxf(x, -15.f), 15.f);
  float e = __expf(2.f * xc);
  return (e - 1.f) / (e + 1.f);
}
// LDS XOR swizzle for [row][64] bf16 A-tiles (G4).
__device__ __forceinline__ int swz(int r, int c) { return r * 64 + (c ^ ((r & 7) << 3)); }

// counted-vmcnt barrier (T4) + scheduler fence (rule #18)
#define VM_BAR(N) do { \
  asm volatile("s_waitcnt vmcnt(" #N ")" ::: "memory"); \
  __builtin_amdgcn_s_barrier(); \
  __builtin_amdgcn_sched_barrier(0); } while (0)

// async global->LDS, 16B per lane (m97: global_load_lds_dwordx4)
__device__ __forceinline__ void gl_lds16(const u16* g, u16* l) {
  __builtin_amdgcn_global_load_lds(
      (const __attribute__((address_space(1))) void*)g,
      (__attribute__((address_space(3))) void*)l, 16, 0, 0);
}
// stage 64x64 A-tile (8 KB) from row-major bf16 (stride ldk) into the swizzled
// LDS image: linear LDS dest + XOR-permuted GLOBAL source chunks (m173).
__device__ __forceinline__ void stageA(const u16* base, int ldk, u16* lA, int t) {
  const int r = t >> 3, q = t & 7, wid = t >> 6;
  const int qs = (q ^ (r & 7)) << 3;                 // (r+32)&7 == r&7
  gl_lds16(base + (size_t)r * ldk + qs, lA + wid * 512);
  gl_lds16(base + (size_t)(r + 32) * ldk + qs, lA + 2048 + wid * 512);
}

// ---------------------------------------------------------------------------
// pre: fused input-cast + weight prep (fragment-major B).
// ---------------------------------------------------------------------------
__global__ __launch_bounds__(256) void hlstm_pre(
    const float* __restrict__ hhat0, const float* __restrict__ h0,
    const float* __restrict__ x, u16* __restrict__ abuf,
    const float* __restrict__ hweight, const float* __restrict__ hbias,
    const float* __restrict__ zw_h, const float* __restrict__ zw_x, const float* __restrict__ zw_b,
    const float* __restrict__ zb_h, const float* __restrict__ zb_x,
    const float* __restrict__ dw_h, const float* __restrict__ dw_x, const float* __restrict__ dw_b,
    const float* __restrict__ weight, const float* __restrict__ bias,
    u16* __restrict__ hw_fr, float* __restrict__ hbias_r,
    u16* __restrict__ w_fr,  float* __restrict__ bias_r,
    u16* __restrict__ whp_fr, u16* __restrict__ wxp_fr, u16* __restrict__ wbp_fr,
    float* __restrict__ bhp_r, float* __restrict__ bxp_r)
{
  if (blockIdx.x < 4096) {
    // ---- cast part: abuf[B][512] = bf16([hhat0 | h0 | x])
    const size_t stride = (size_t)4096 * 256;
    for (size_t i = (size_t)blockIdx.x * 256 + threadIdx.x;
         i < (size_t)BATCH * 64; i += stride) {
      const size_t b = i >> 6; const int c = (int)(i & 63);
      const float* src;
      if (c < 16)      src = hhat0 + b * 128 + c * 8;
      else if (c < 48) src = h0 + b * 256 + (size_t)(c - 16) * 8;
      else             src = x + b * 128 + (size_t)(c - 48) * 8;
      float4 v0 = ((const float4*)src)[0];
      float4 v1 = ((const float4*)src)[1];
      alignas(16) u16 o[8] = {f2b(v0.x), f2b(v0.y), f2b(v0.z), f2b(v0.w),
                              f2b(v1.x), f2b(v1.y), f2b(v1.z), f2b(v1.w)};
      *(uint4*)(abuf + i * 8) = *(const uint4*)o;
    }
    return;
  }
  // ---- prep part: fragment-major images.
  const int tid = (blockIdx.x - 4096) * 256 + threadIdx.x;
  const int nt  = 512 * 256;

  // hw_fr: 16 tiles (hb*8+s), phys col = g*128 + hb*64 + hh
  for (int i = tid; i < 16 * 16384; i += nt) {
    int tile = i >> 14, r = i & 16383;
    int wc = r >> 12, h = (r >> 11) & 1, g = (r >> 9) & 3;
    int lane = (r >> 3) & 63, j = r & 7;
    int hb = tile >> 3, s = tile & 7;
    int k = s * 64 + h * 32 + (lane >> 4) * 8 + j;
    int col = g * 128 + hb * 64 + wc * 16 + (lane & 15);
    hw_fr[i] = f2b(hweight[k * 512 + col]);
  }
  // w_fr: 24 tiles (hb*6+s), phys col = g*256 + hb*64 + hh
  for (int i = tid; i < 24 * 16384; i += nt) {
    int tile = i >> 14, r = i & 16383;
    int wc = r >> 12, h = (r >> 11) & 1, g = (r >> 9) & 3;
    int lane = (r >> 3) & 63, j = r & 7;
    int hb = tile / 6, s = tile % 6;
    int k = s * 64 + h * 32 + (lane >> 4) * 8 + j;
    int col = g * 256 + hb * 64 + wc * 16 + (lane & 15);
    w_fr[i] = f2b(weight[k * 1024 + col]);
  }
  // folded hyper fragments: 3 mats x 8 tiles (hb*2+s); W'[k][(g,h)] = sum_e zw*dw
  for (int i = tid; i < 3 * 8 * 16384; i += nt) {
    int mat = i / (8 * 16384), rem = i % (8 * 16384);
    int tile = rem >> 14, r = rem & 16383;
    int wc = r >> 12, h = (r >> 11) & 1, g = (r >> 9) & 3;
    int lane = (r >> 3) & 63, j = r & 7;
    int hb = tile >> 1, s = tile & 1;
    int k = s * 64 + h * 32 + (lane >> 4) * 8 + j;       // 0..127
    int colh = hb * 64 + wc * 16 + (lane & 15);
    const float* zw = (mat == 0) ? zw_h : (mat == 1) ? zw_x : zw_b;
    const float* dw = (mat == 0) ? dw_h : (mat == 1) ? dw_x : dw_b;
    float sv = 0.f;
#pragma unroll
    for (int e = 0; e < 16; ++e)
      sv += zw[k * 64 + g * 16 + e] * dw[g * 4096 + e * 256 + colh];
    u16* dst = (mat == 0) ? whp_fr : (mat == 1) ? wxp_fr : wbp_fr;
    dst[rem] = f2b(sv);
  }
  // bias folds (virtual order hb*256 + g*64 + hh)
  for (int i = tid; i < 1024; i += nt) {
    int hb = i >> 8, g = (i >> 6) & 3, hh = i & 63;
    int h = hb * 64 + hh;
    float sh = 0.f, sx = 0.f;
#pragma unroll
    for (int e = 0; e < 16; ++e) {
      sh += zb_h[g * 16 + e] * dw_h[g * 4096 + e * 256 + h];
      sx += zb_x[g * 16 + e] * dw_x[g * 4096 + e * 256 + h];
    }
    bhp_r[i] = sh; bxp_r[i] = sx;
    bias_r[i] = bias[g * 256 + h];
  }
  for (int i = tid; i < 512; i += nt) {
    int gate = (i >> 6) & 3, hb = i >> 8, hh = i & 63;
    hbias_r[i] = hbias[gate * 128 + hb * 64 + hh];
  }
}

// ---------------------------------------------------------------------------
// k1: hyper GEMM (K=512, 8 steps) + hyper LSTM. 2048 blocks x 256 threads.
// A: LDS ring-3 (24 KB); B: single-buffered register fragments.
// ---------------------------------------------------------------------------
__global__ __launch_bounds__(256, 3) void hlstm_k1(
    const u16* __restrict__ abuf, const float* __restrict__ chat0,
    const u16* __restrict__ hw_fr, const float* __restrict__ hbias_r,
    float* __restrict__ d_out, u16* __restrict__ hbuf)
{
  __shared__ alignas(16) u16 lA[3][64 * 64];
  const int f = blockIdx.x;                 // 0..2047
  const int xcd = f & 7, s2 = f >> 3;
  const int rb = xcd * 128 + (s2 >> 1), hb = s2 & 1;
  const int t = threadIdx.x;
  const int lane = t & 63, wc = t >> 6;
  const int lr = lane & 15, kg = lane >> 4;

  f32x4 acc[4][4];
  const f32x4 zzero = {0.f, 0.f, 0.f, 0.f};
#pragma unroll
  for (int mf = 0; mf < 4; ++mf)
#pragma unroll
    for (int g = 0; g < 4; ++g) acc[mf][g] = zzero;

  const u16* arow = abuf + (size_t)rb * 64 * 512;

  bf16x8 breg[8];
  auto loadB = [&](const u16* bt) {
#pragma unroll
    for (int h = 0; h < 2; ++h)
#pragma unroll
      for (int g = 0; g < 4; ++g)
        breg[h * 4 + g] = *(const bf16x8*)&bt[((wc * 2 + h) * 4 + g) * 512 + lane * 8];
  };
  auto sweep = [&](f32x4 (&ac)[4][4], const u16* cA) {
    __builtin_amdgcn_s_setprio(1);
#pragma unroll
    for (int h = 0; h < 2; ++h)
#pragma unroll
      for (int mf = 0; mf < 4; ++mf) {
        bf16x8 afr = *(const bf16x8*)&cA[swz(mf * 16 + lr, h * 32 + kg * 8)];
#pragma unroll
        for (int g = 0; g < 4; ++g)
          ac[mf][g] = __builtin_amdgcn_mfma_f32_16x16x32_bf16(afr, breg[h * 4 + g], ac[mf][g], 0, 0, 0);
      }
    __builtin_amdgcn_s_setprio(0);
  };

  // prologue: A(0), A(1) staged; B(0) issued. vmcnt(8) -> A done, B(0) rides.
  stageA(arow + 0 * 64, 512, lA[0], t);
  stageA(arow + 1 * 64, 512, lA[1], t);
  loadB(hw_fr + (size_t)(hb * 8 + 0) * 16384);
  VM_BAR(8);

#pragma unroll
  for (int ks = 0; ks < 8; ++ks) {
    if (ks < 6) stageA(arow + (ks + 2) * 64, 512, lA[(ks + 2) % 3], t);
    sweep(acc, lA[ks % 3]);                 // waits on breg (B(ks)) via compiler
    if (ks < 7) loadB(hw_fr + (size_t)(hb * 8 + ks + 1) * 16384);
    if (ks < 6)       VM_BAR(10);           // A(ks+2):2 + B(ks+1):8 in flight
    else if (ks == 6) VM_BAR(8);            // B(7):8 in flight
  }

  float hb4[4];
#pragma unroll
  for (int g = 0; g < 4; ++g) hb4[g] = hbias_r[hb * 256 + g * 64 + wc * 16 + lr];
  const int zc = hb * 64 + wc * 16 + lr;
  float* out_hh = d_out + (size_t)BATCH * 512;
  float* out_ch = d_out + (size_t)BATCH * 640;
#pragma unroll
  for (int mf = 0; mf < 4; ++mf)
#pragma unroll
    for (int r = 0; r < 4; ++r) {
      const int row = rb * 64 + mf * 16 + kg * 4 + r;
      const float gi = acc[mf][0][r] + hb4[0];
      const float gg = acc[mf][1][r] + hb4[1];
      const float gf = acc[mf][2][r] + hb4[2];
      const float go = acc[mf][3][r] + hb4[3];
      const float c0v = chat0[(size_t)row * 128 + zc];
      const float c1v = sigf(gf) * c0v + sigf(gi) * tanhfast(gg);
      const float h1v = sigf(go) * tanhfast(c1v);
      out_hh[(size_t)row * 128 + zc] = h1v;
      out_ch[(size_t)row * 128 + zc] = c1v;
      hbuf[(size_t)row * 128 + zc] = f2b(h1v);
    }
}

// ---------------------------------------------------------------------------
// k2: hyper-first 12 K-steps (s0-1 d_yh -> dsc ; s2-3 d_yx -> dsc ; s4-9 main
// gpre ; s9 acc*=dsc ; s10-11 d_yb MFMA C-in). 4096 blocks x 256 threads.
// A: LDS ring-2 with content-reuse skip at steps 2,3; B: reg fragments;
// dsc in per-thread LDS slots. LDS 48 KB -> 3 blocks/CU; (256,3).
// ---------------------------------------------------------------------------
__global__ __launch_bounds__(256, 3) void hlstm_k2(
    const u16* __restrict__ abuf, const u16* __restrict__ hbuf,
    const float* __restrict__ c0,
    const u16* __restrict__ w_fr, const float* __restrict__ bias_r,
    const u16* __restrict__ whp_fr, const u16* __restrict__ wxp_fr, const u16* __restrict__ wbp_fr,
    const float* __restrict__ bhp_r, const float* __restrict__ bxp_r,
    float* __restrict__ d_out)
{
  __shared__ alignas(16) u16 lA[2][64 * 64];     // 16 KB (ring-2)
  __shared__ alignas(16) unsigned ldsc[8192];    // 32 KB packed dscale
  const int f = blockIdx.x;                 // 0..4095
  const int xcd = f & 7, s4 = f >> 3;
  const int rb = xcd * 128 + (s4 >> 2), hb = s4 & 3;
  const int t = threadIdx.x;
  const int lane = t & 63, wc = t >> 6;
  const int lr = lane & 15, kg = lane >> 4;

  const u16* amain = abuf + (size_t)rb * 64 * 512 + 128;   // [h0|x] cols, ld 512
  const u16* ahyp  = hbuf + (size_t)rb * 64 * 128;         // ld 128

  // steps: 0..3 hyper (Wh',Wx'), 4..9 main, 10..11 hyper (Wb')
  auto aptr = [&](int s) -> const u16* {
    if (s >= 4 && s < 10) return amain + (s - 4) * 64;
    return ahyp + (s & 1) * 64;
  };
  auto aldk = [&](int s) -> int { return (s >= 4 && s < 10) ? 512 : 128; };
  auto bptr = [&](int s) -> const u16* {
    if (s < 2)  return whp_fr + (size_t)(hb * 2 + s) * 16384;
    if (s < 4)  return wxp_fr + (size_t)(hb * 2 + s - 2) * 16384;
    if (s < 10) return w_fr  + (size_t)(hb * 6 + s - 4) * 16384;
    return wbp_fr + (size_t)(hb * 2 + s - 10) * 16384;
  };

  f32x4 acc[4][4];
  const f32x4 zzero = {0.f, 0.f, 0.f, 0.f};
#pragma unroll
  for (int mf = 0; mf < 4; ++mf)
#pragma unroll
    for (int g = 0; g < 4; ++g) acc[mf][g] = zzero;

  bf16x8 breg[8];
  auto loadB = [&](const u16* bt) {
#pragma unroll
    for (int h = 0; h < 2; ++h)
#pragma unroll
      for (int g = 0; g < 4; ++g)
        breg[h * 4 + g] = *(const bf16x8*)&bt[((wc * 2 + h) * 4 + g) * 512 + lane * 8];
  };
  auto sweep = [&](f32x4 (&ac)[4][4], const u16* cA) {
    __builtin_amdgcn_s_setprio(1);
#pragma unroll
    for (int h = 0; h < 2; ++h)
#pragma unroll
      for (int mf = 0; mf < 4; ++mf) {
        bf16x8 afr = *(const bf16x8*)&cA[swz(mf * 16 + lr, h * 32 + kg * 8)];
#pragma unroll
        for (int g = 0; g < 4; ++g)
          ac[mf][g] = __builtin_amdgcn_mfma_f32_16x16x32_bf16(afr, breg[h * 4 + g], ac[mf][g], 0, 0, 0);
      }
    __builtin_amdgcn_s_setprio(0);
  };

  // prologue: A(0)->lA0, A(1)->lA1 staged; B(0) issued.
  stageA(aptr(0), aldk(0), lA[0], t);
  stageA(aptr(1), aldk(1), lA[1], t);
  loadB(bptr(0));
  VM_BAR(8);

#pragma unroll
  for (int s = 0; s < 12; ++s) {
    // stage(s+1): steps 1..3 need no stage (A(1) prologue-staged; A(2),A(3)
    // content-identical to A(0),A(1) in the same ring-2 buffers).
    if (s >= 3 && s < 11) stageA(aptr(s + 1), aldk(s + 1), lA[(s + 1) & 1], t);
    if (s == 2 || s == 4) {                 // new phase: re-zero single acc
#pragma unroll
      for (int mf = 0; mf < 4; ++mf)
#pragma unroll
        for (int g = 0; g < 4; ++g) acc[mf][g] = zzero;
    }
    sweep(acc, lA[s & 1]);                  // waits on breg (B(s)) via compiler
    if (s < 11) loadB(bptr(s + 1));

    if (s == 1) {                           // ldsc = pack(d_yh + bh')
      float bh4[4];
#pragma unroll
      for (int g = 0; g < 4; ++g) bh4[g] = bhp_r[hb * 256 + g * 64 + wc * 16 + lr];
#pragma unroll
      for (int mf = 0; mf < 4; ++mf)
#pragma unroll
        for (int gp = 0; gp < 2; ++gp) {
          const int g0 = gp * 2, g1 = gp * 2 + 1;
          uint4 v;
          v.x = pk2(acc[mf][g0][0] + bh4[g0], acc[mf][g0][1] + bh4[g0]);
          v.y = pk2(acc[mf][g0][2] + bh4[g0], acc[mf][g0][3] + bh4[g0]);
          v.z = pk2(acc[mf][g1][0] + bh4[g1], acc[mf][g1][1] + bh4[g1]);
          v.w = pk2(acc[mf][g1][2] + bh4[g1], acc[mf][g1][3] + bh4[g1]);
          *(uint4*)&ldsc[(mf * 2 + gp) * 1024 + t * 4] = v;
        }
    } else if (s == 3) {                    // ldsc *= (d_yx + bx')
      float bx4[4];
#pragma unroll
      for (int g = 0; g < 4; ++g) bx4[g] = bxp_r[hb * 256 + g * 64 + wc * 16 + lr];
#pragma unroll
      for (int mf = 0; mf < 4; ++mf)
#pragma unroll
        for (int gp = 0; gp < 2; ++gp) {
          const int g0 = gp * 2, g1 = gp * 2 + 1;
          uint4 v = *(const uint4*)&ldsc[(mf * 2 + gp) * 1024 + t * 4];
          v.x = pk2(upk_lo(v.x) * (acc[mf][g0][0] + bx4[g0]),
                    upk_hi(v.x) * (acc[mf][g0][1] + bx4[g0]));
          v.y = pk2(upk_lo(v.y) * (acc[mf][g0][2] + bx4[g0]),
                    upk_hi(v.y) * (acc[mf][g0][3] + bx4[g0]));
          v.z = pk2(upk_lo(v.z) * (acc[mf][g1][0] + bx4[g1]),
                    upk_hi(v.z) * (acc[mf][g1][1] + bx4[g1]));
          v.w = pk2(upk_lo(v.w) * (acc[mf][g1][2] + bx4[g1]),
                    upk_hi(v.w) * (acc[mf][g1][3] + bx4[g1]));
          *(uint4*)&ldsc[(mf * 2 + gp) * 1024 + t * 4] = v;
        }
    } else if (s == 9) {                    // acc(gpre) *= dscale
#pragma unroll
      for (int mf = 0; mf < 4; ++mf)
#pragma unroll
        for (int gp = 0; gp < 2; ++gp) {
          const int g0 = gp * 2, g1 = gp * 2 + 1;
          uint4 v = *(const uint4*)&ldsc[(mf * 2 + gp) * 1024 + t * 4];
          acc[mf][g0][0] *= upk_lo(v.x);
          acc[mf][g0][1] *= upk_hi(v.x);
          acc[mf][g0][2] *= upk_lo(v.y);
          acc[mf][g0][3] *= upk_hi(v.y);
          acc[mf][g1][0] *= upk_lo(v.z);
          acc[mf][g1][1] *= upk_hi(v.z);
          acc[mf][g1][2] *= upk_lo(v.w);
          acc[mf][g1][3] *= upk_hi(v.w);
        }
    }
    if (s < 11) VM_BAR(8);                  // forces stageA(s+1) when staged
  }

  // ---- epilogue: main LSTM cell (acc = gpre*dscale + d_yb)
  const int hcol = hb * 64 + wc * 16 + lr;
  float b4[4];
#pragma unroll
  for (int g = 0; g < 4; ++g) b4[g] = bias_r[hb * 256 + g * 64 + wc * 16 + lr];
  float* out_c1 = d_out + (size_t)BATCH * 256;
#pragma unroll
  for (int mf = 0; mf < 4; ++mf)
#pragma unroll
    for (int r = 0; r < 4; ++r) {
      const int row = rb * 64 + mf * 16 + kg * 4 + r;
      const float gi = acc[mf][0][r] + b4[0];
      const float gg = acc[mf][1][r] + b4[1];
      const float gf = acc[mf][2][r] + b4[2];
      const float go = acc[mf][3][r] + b4[3];
      const float c0v = c0[(size_t)row * 256 + hcol];
      const float c1v = sigf(gf) * c0v + sigf(gi) * tanhfast(gg);
      const float h1v = sigf(go) * tanhfast(c1v);
      d_out[(size_t)row * 256 + hcol]  = h1v;
      out_c1[(size_t)row * 256 + hcol] = c1v;
    }
}

// ---------------------------------------------------------------------------
extern "C" void kernel_launch(void* const* d_in, const int* in_sizes, int n_in,
                              void* d_out, int out_size, void* d_ws, size_t ws_size,
                              hipStream_t stream)
{
  (void)in_sizes; (void)n_in; (void)out_size; (void)ws_size;
  const float* x       = (const float*)d_in[0];
  const float* h0      = (const float*)d_in[1];
  const float* c0      = (const float*)d_in[2];
  const float* hhat0   = (const float*)d_in[3];
  const float* chat0   = (const float*)d_in[4];
  const float* hweight = (const float*)d_in[5];
  const float* hbias   = (const float*)d_in[6];
  const float* zw_h    = (const float*)d_in[7];
  const float* zw_x    = (const float*)d_in[8];
  const float* zw_b    = (const float*)d_in[9];
  const float* zb_h    = (const float*)d_in[10];
  const float* zb_x    = (const float*)d_in[11];
  const float* dw_h    = (const float*)d_in[12];
  const float* dw_x    = (const float*)d_in[13];
  const float* dw_b    = (const float*)d_in[14];
  const float* weight  = (const float*)d_in[15];
  const float* bias    = (const float*)d_in[16];

  // workspace layout (bytes, 16B-aligned); total ~86 MB
  char* wsb = (char*)d_ws;
  u16*   abuf    = (u16*)(wsb + 0);              // B*512*2   = 67108864
  u16*   hbuf    = (u16*)(wsb + 67108864);       // B*128*2   = 16777216
  u16*   hw_fr   = (u16*)(wsb + 83886080);       // 16*16384*2 = 524288
  u16*   w_fr    = (u16*)(wsb + 84410368);       // 24*16384*2 = 786432
  u16*   whp_fr  = (u16*)(wsb + 85196800);       // 8*16384*2  = 262144
  u16*   wxp_fr  = (u16*)(wsb + 85458944);
  u16*   wbp_fr  = (u16*)(wsb + 85721088);
  float* hbias_r = (float*)(wsb + 85983232);     // 512*4
  float* bias_r  = (float*)(wsb + 85985280);     // 1024*4
  float* bhp_r   = (float*)(wsb + 85989376);     // 1024*4
  float* bxp_r   = (float*)(wsb + 85993472);     // 1024*4

  hlstm_pre<<<dim3(4608), dim3(256), 0, stream>>>(
      hhat0, h0, x, abuf,
      hweight, hbias, zw_h, zw_x, zw_b, zb_h, zb_x, dw_h, dw_x, dw_b, weight, bias,
      hw_fr, hbias_r, w_fr, bias_r, whp_fr, wxp_fr, wbp_fr, bhp_r, bxp_r);

  hlstm_k1<<<dim3(2048), dim3(256), 0, stream>>>(
      abuf, chat0, hw_fr, hbias_r, (float*)d_out, hbuf);

  hlstm_k2<<<dim3(4096), dim3(256), 0, stream>>>(
      abuf, hbuf, c0, w_fr, bias_r, whp_fr, wxp_fr, wbp_fr, bhp_r, bxp_r, (float*)d_out);
}